// Round 20
// baseline (1762.568 us; speedup 1.0000x reference)
//
#include <hip/hip_runtime.h>

typedef unsigned short u16;
typedef unsigned int u32;
typedef __attribute__((ext_vector_type(8))) short short8;
typedef __attribute__((ext_vector_type(8))) u16 ushort8;
typedef __attribute__((ext_vector_type(4))) float f32x4;
typedef __attribute__((ext_vector_type(4))) u32 u32x4;

#define T_TOK 2048
#define H_DIM 2048
#define NEXP 64
#define I_DIM 1408
#define SI_DIM 2816
#define BM 128
#define BK 64
#define MAXT 512

__device__ __forceinline__ u16 f2bf(float f) {
    u32 u = __builtin_bit_cast(u32, f);
    u32 r = u + 0x7FFFu + ((u >> 16) & 1u);
    return (u16)(r >> 16);
}

__device__ __forceinline__ float bf2f(u16 v) {
    u32 u = ((u32)v) << 16;
    return __builtin_bit_cast(float, u);
}

// HW packed f32->bf16 (RNE) — one VALU op per 2 elements.
__device__ __forceinline__ u32 cvtpk(float lo, float hi) {
    u32 r;
    asm("v_cvt_pk_bf16_f32 %0, %1, %2" : "=v"(r) : "v"(lo), "v"(hi));
    return r;
}

__device__ __forceinline__ ushort8 cvt8(f32x4 a, f32x4 b) {
    u32x4 p;
    p[0] = cvtpk(a[0], a[1]);
    p[1] = cvtpk(a[2], a[3]);
    p[2] = cvtpk(b[0], b[1]);
    p[3] = cvtpk(b[2], b[3]);
    return __builtin_bit_cast(ushort8, p);
}

__device__ __forceinline__ f32x4 mfma16(short8 a, short8 b, f32x4 c) {
    return __builtin_amdgcn_mfma_f32_16x16x32_bf16(a, b, c, 0, 0, 0);
}

__device__ __forceinline__ void gld_lds16(const void* g, void* l) {
    __builtin_amdgcn_global_load_lds(
        (const __attribute__((address_space(1))) void*)(g),
        (__attribute__((address_space(3))) void*)(l), 16, 0, 0);
}

// ---------------- x -> bf16 ----------------
__global__ __launch_bounds__(256) void k_cvt(const float* __restrict__ x, u16* __restrict__ xb) {
    int i = (blockIdx.x * 256 + threadIdx.x) * 8;
    f32x4 v0 = *(const f32x4*)(x + i);
    f32x4 v1 = *(const f32x4*)(x + i + 4);
    *(ushort8*)(xb + i) = cvt8(v0, v1);
}

// ---------------- gating logits: f64 accumulation ----------------
__global__ __launch_bounds__(256) void k_gate_logits(const float* __restrict__ x,
        const float* __restrict__ gw, float* __restrict__ logits) {
    __shared__ float xs[8][65];
    __shared__ float wsh[64][65];
    int tid = threadIdx.x;
    int t0 = blockIdx.x * 8;
    double acc0 = 0.0, acc1 = 0.0;
    int e = tid & 63, tg = tid >> 6; // tg in [0,4)
    for (int k0 = 0; k0 < H_DIM; k0 += 64) {
        #pragma unroll
        for (int s = 0; s < 2; ++s) {
            int idx = s * 256 + tid;
            int r = idx >> 6, k = idx & 63;
            xs[r][k] = x[(size_t)(t0 + r) * H_DIM + k0 + k];
        }
        #pragma unroll
        for (int s = 0; s < 16; ++s) {
            int idx = s * 256 + tid;
            int r = idx >> 6, k = idx & 63;
            wsh[r][k] = gw[(size_t)r * H_DIM + k0 + k];
        }
        __syncthreads();
        #pragma unroll 8
        for (int k = 0; k < 64; ++k) {
            double wv = (double)wsh[e][k];
            acc0 += (double)xs[tg][k] * wv;
            acc1 += (double)xs[tg + 4][k] * wv;
        }
        __syncthreads();
    }
    logits[(size_t)(t0 + tg) * NEXP + e] = (float)acc0;
    logits[(size_t)(t0 + tg + 4) * NEXP + e] = (float)acc1;
}

// ---------------- per-token group-restricted top-k ----------------
__global__ __launch_bounds__(256) void k_topk(const float* __restrict__ logits,
        const float* __restrict__ ebias, int* __restrict__ topk_idx,
        float* __restrict__ topk_w, int* __restrict__ counts) {
    __shared__ float bsh[64];
    if (threadIdx.x < 64) bsh[threadIdx.x] = ebias[threadIdx.x];
    __syncthreads();
    int t = blockIdx.x * 256 + threadIdx.x;
    float sc[64];
    #pragma unroll
    for (int e2 = 0; e2 < 64; ++e2) {
        float lg = logits[(size_t)t * 64 + e2];
        sc[e2] = 1.0f / (1.0f + expf(-lg));
    }
    float gsc[8];
    #pragma unroll
    for (int g = 0; g < 8; ++g) {
        float m1 = -1e30f, m2 = -1e30f;
        #pragma unroll
        for (int j = 0; j < 8; ++j) {
            float v = sc[g * 8 + j] + bsh[g * 8 + j];
            if (v > m1) { m2 = m1; m1 = v; }
            else if (v > m2) { m2 = v; }
        }
        gsc[g] = m1 + m2;
    }
    u32 gmask = 0;
    #pragma unroll
    for (int it = 0; it < 4; ++it) {
        float best = -1e30f; int bi = 0;
        #pragma unroll
        for (int g = 0; g < 8; ++g) {
            bool ok = !((gmask >> g) & 1u);
            if (ok && gsc[g] > best) { best = gsc[g]; bi = g; }
        }
        gmask |= 1u << bi;
    }
    unsigned long long avail = 0ull;
    #pragma unroll
    for (int g = 0; g < 8; ++g)
        if ((gmask >> g) & 1u) avail |= (0xFFull << (g * 8));
    float wsum = 0.f;
    int idx[8]; float wv[8];
    #pragma unroll
    for (int it = 0; it < 8; ++it) {
        float best = -1e30f, bw = 0.f; int bi = 0;
        #pragma unroll
        for (int e2 = 0; e2 < 64; ++e2) {
            bool ok = (avail >> e2) & 1ull;
            float v = sc[e2] + bsh[e2];
            if (ok && v > best) { best = v; bi = e2; bw = sc[e2]; }
        }
        avail &= ~(1ull << bi);
        idx[it] = bi; wv[it] = bw; wsum += bw;
    }
    float scale = 2.5f / (wsum + 1e-20f);
    #pragma unroll
    for (int it = 0; it < 8; ++it) {
        topk_idx[t * 8 + it] = idx[it];
        topk_w[t * 8 + it] = wv[it] * scale;
        atomicAdd(&counts[idx[it]], 1);
    }
}

// ---------------- prefix sum + unified XCD-grouped tile lists ----------------
__global__ void k_prefix(const int* __restrict__ counts, int* __restrict__ offsets,
                         int* __restrict__ tiles_gu, int* __restrict__ tiles_dn) {
    if (threadIdx.x == 0) {
        int run = 0;
        for (int e = 0; e < 64; ++e) { offsets[e] = run; run += counts[e]; }
        offsets[64] = run;
        for (int i = 0; i < MAXT; ++i) { tiles_gu[i] = -1; tiles_dn[i] = -1; }
        int sg[8] = {0,0,0,0,0,0,0,0};
        int sd[8] = {0,0,0,0,0,0,0,0};
        for (int j = 0; j < SI_DIM / 64; ++j) {           // 44 shared gateup panels
            int xcd = j & 7;
            int pos = xcd + 8 * sg[xcd];
            if (pos < MAXT) { tiles_gu[pos] = (64 << 16) | (j * 64); sg[xcd]++; }
        }
        for (int j = 0; j < H_DIM / 128; ++j) {           // 16 shared down panels
            int xcd = j & 7;
            int pos = xcd + 8 * sd[xcd];
            if (pos < MAXT) { tiles_dn[pos] = (64 << 16) | (j * 128); sd[xcd]++; }
        }
        for (int e = 0; e < 64; ++e) {
            int xcd = e & 7;
            int c = counts[e];
            for (int m0 = 0; m0 < c; m0 += BM) {
                int pg = xcd + 8 * sg[xcd];
                if (pg < MAXT) { tiles_gu[pg] = (e << 16) | m0; sg[xcd]++; }
                int pd = xcd + 8 * sd[xcd];
                if (pd < MAXT) { tiles_dn[pd] = (e << 16) | m0; sd[xcd]++; }
            }
        }
    }
}

// ---------------- scatter (t,k) -> per-expert lists + inverse slot map ------
__global__ __launch_bounds__(256) void k_scatter(const int* __restrict__ topk_idx,
        const float* __restrict__ topk_w, const int* __restrict__ offsets,
        int* __restrict__ fill, int* __restrict__ tok_list, float* __restrict__ w_list,
        int* __restrict__ slot_of) {
    int gid = blockIdx.x * 256 + threadIdx.x;
    int t = gid >> 3;
    int e = topk_idx[gid];
    int pos = offsets[e] + atomicAdd(&fill[e], 1);
    tok_list[pos] = t;
    w_list[pos] = topk_w[gid];
    slot_of[gid] = pos;
}

// ---------------- unified gate+up+silu*mul grouped GEMM ----------------
// 128m x 64n(gate+up), BK=64, 4 waves, dbuf LDS, one barrier/K-step.
// A: global_load_lds (source-preswizzled). B: BURST staging — each thread reads
// 32 CONTIGUOUS floats (128B) per matrix covering 2 K-steps (chunk=128 cols),
// maximizing DRAM row-buffer locality. q=tid&3: q<2 holds even-step cols,
// q>=2 odd-step cols; writes go to the buffer that is free at that point.
__global__ __launch_bounds__(256, 2) void k_gateup(
        const u16* __restrict__ xb,
        const float* __restrict__ gr, const float* __restrict__ ur,
        const float* __restrict__ gs, const float* __restrict__ us,
        const int* __restrict__ offsets, const int* __restrict__ tok_list,
        const int* __restrict__ tiles,
        u16* __restrict__ inter_r, u16* __restrict__ inter_s) {
    int tt = tiles[blockIdx.x];
    if (tt < 0) return;
    int e = tt >> 16;
    const float *Bg, *Bu; u16* op; const int* tl;
    int m0, seg, n, i0, Irows;
    if (e < 64) {
        m0 = tt & 0xFFFF; seg = offsets[e]; n = offsets[e + 1] - seg;
        if (n <= 0 || m0 >= n) return;
        i0 = blockIdx.y * 64;
        Bg = gr + (size_t)e * I_DIM * H_DIM;
        Bu = ur + (size_t)e * I_DIM * H_DIM;
        op = inter_r; Irows = I_DIM; tl = tok_list;
    } else {
        if (blockIdx.y >= T_TOK / BM) return;
        i0 = tt & 0xFFFF; m0 = blockIdx.y * BM; seg = 0; n = T_TOK;
        Bg = gs; Bu = us;
        op = inter_s; Irows = SI_DIM; tl = nullptr;
    }

    __shared__ u16 As[2][BM * BK];    // 2 x 16KB, linear (source-preswizzled)
    __shared__ u16 Bsg[2][64 * BK];   // 2 x 8KB, xor-swizzled
    __shared__ u16 Bsu[2][64 * BK];   // 2 x 8KB

    int tid = threadIdx.x;
    int w = tid >> 6, lane = tid & 63;

    // A via gld_lds (unchanged from r18)
    const u16* agsrc[4];
    #pragma unroll
    for (int s = 0; s < 4; ++s) {
        int slot = s * 256 + tid;
        int r = slot >> 3, cb = slot & 7;
        int p = m0 + r; if (p >= n) p = n - 1;
        int tok = tl ? tl[seg + p] : p;
        agsrc[s] = xb + (size_t)tok * H_DIM + ((cb ^ (r & 7)) * 8);
    }
    auto gldA = [&](int t, int buf) {
        #pragma unroll
        for (int s = 0; s < 4; ++s)
            gld_lds16(agsrc[s] + t * BK, (u16*)As[buf] + s * 2048 + w * 512);
    };

    // B burst: row br = tid>>2, q = tid&3; 32 contiguous floats per matrix.
    int br = tid >> 2, bq = tid & 3;
    const float* bgsrc = Bg + (size_t)(i0 + br) * H_DIM + bq * 32;
    const float* busrc = Bu + (size_t)(i0 + br) * H_DIM + bq * 32;
    int bdst[4];
    #pragma unroll
    for (int j = 0; j < 4; ++j)
        bdst[j] = br * BK + (((((bq & 1) * 4 + j)) ^ (br & 7)) * 8);
    bool oddgrp = (bq >> 1) != 0;      // holds odd-step columns -> writes buf1

    f32x4 zero; zero[0] = 0.f; zero[1] = 0.f; zero[2] = 0.f; zero[3] = 0.f;
    f32x4 accg[2][4], accu[2][4];
    #pragma unroll
    for (int a = 0; a < 2; ++a)
        #pragma unroll
        for (int b = 0; b < 4; ++b) { accg[a][b] = zero; accu[a][b] = zero; }

    f32x4 bG[8], bU[8];                // one chunk (2 K-steps) of this thread's B
    auto burst = [&](int C) {
        int k0 = C * 128;
        #pragma unroll
        for (int j = 0; j < 8; ++j) {
            bG[j] = *(const f32x4*)(bgsrc + k0 + j * 4);
            bU[j] = *(const f32x4*)(busrc + k0 + j * 4);
        }
    };
    auto dswE = [&]() {                // even-step cols -> buf0 (q<2 threads)
        if (!oddgrp) {
            #pragma unroll
            for (int j = 0; j < 4; ++j) {
                *(ushort8*)(&Bsg[0][bdst[j]]) = cvt8(bG[2 * j], bG[2 * j + 1]);
                *(ushort8*)(&Bsu[0][bdst[j]]) = cvt8(bU[2 * j], bU[2 * j + 1]);
            }
        }
    };
    auto dswO = [&]() {                // odd-step cols -> buf1 (q>=2 threads)
        if (oddgrp) {
            #pragma unroll
            for (int j = 0; j < 4; ++j) {
                *(ushort8*)(&Bsg[1][bdst[j]]) = cvt8(bG[2 * j], bG[2 * j + 1]);
                *(ushort8*)(&Bsu[1][bdst[j]]) = cvt8(bU[2 * j], bU[2 * j + 1]);
            }
        }
    };
    auto mmaStep = [&](int buf) {
        #pragma unroll
        for (int ks = 0; ks < 2; ++ks) {
            short8 a[2];
            #pragma unroll
            for (int fm = 0; fm < 2; ++fm) {
                int row = w * 32 + fm * 16 + (lane & 15);
                int cb = ks * 4 + (lane >> 4);
                a[fm] = *(const short8*)(&As[buf][row * BK + ((cb ^ (row & 7)) * 8)]);
            }
            #pragma unroll
            for (int fn = 0; fn < 4; ++fn) {
                int brow = fn * 16 + (lane & 15);
                int cb = ks * 4 + (lane >> 4);
                int boff = brow * BK + ((cb ^ (brow & 7)) * 8);
                short8 bg = *(const short8*)(&Bsg[buf][boff]);
                short8 bu = *(const short8*)(&Bsu[buf][boff]);
                accg[0][fn] = mfma16(a[0], bg, accg[0][fn]);
                accg[1][fn] = mfma16(a[1], bg, accg[1][fn]);
                accu[0][fn] = mfma16(a[0], bu, accu[0][fn]);
                accu[1][fn] = mfma16(a[1], bu, accu[1][fn]);
            }
        }
    };

    const int NK = H_DIM / BK; // 32, even; chunks of 2 steps
    gldA(0, 0);
    burst(0);
    dswE(); dswO();            // chunk0: even->buf0, odd->buf1
    __syncthreads();
    for (int t = 0; t < NK; t += 2) {
        // even step t: reads buf0 (step t). Regs hold chunk t/2 (or t/2+1 after burst).
        if (t + 1 < NK) gldA(t + 1, 1);
        if (t > 0) dswO();                 // chunk t/2 odd -> buf1 (for step t+1)
        if (t + 2 < NK) burst(t / 2 + 1);  // regs now free; fetch next chunk
        mmaStep(0);
        __syncthreads();
        if (t + 1 < NK) {
            // odd step t+1: reads buf1 (step t+1)
            if (t + 2 < NK) gldA(t + 2, 0);
            if (t + 2 < NK) dswE();        // chunk t/2+1 even -> buf0 (for step t+2)
            mmaStep(1);
            __syncthreads();
        }
    }

    int r0 = (lane >> 4) * 4, cc = lane & 15;
    #pragma unroll
    for (int fm = 0; fm < 2; ++fm) {
        #pragma unroll
        for (int r = 0; r < 4; ++r) {
            int p = m0 + w * 32 + fm * 16 + r0 + r;
            if (p < n) {
                size_t rowb = (size_t)(seg + p) * Irows + i0;
                #pragma unroll
                for (int fn = 0; fn < 4; ++fn) {
                    float g = accg[fm][fn][r], u = accu[fm][fn][r];
                    float val = g / (1.0f + expf(-g)) * u;
                    op[rowb + fn * 16 + cc] = f2bf(val);
                }
            }
        }
    }
}

// ---------------- unified down-proj grouped GEMM (NO atomics) ----------------
// 128m x 128n, BK=64, 4 waves. A via gld_lds; B BURST: each thread reads 64
// CONTIGUOUS floats (256B) per chunk (2 K-steps). q=tid&1 even/odd split.
__global__ __launch_bounds__(256, 2) void k_down(
        const u16* __restrict__ inter_r, const u16* __restrict__ inter_s,
        const float* __restrict__ dr, const float* __restrict__ dsw,
        const int* __restrict__ offsets, const int* __restrict__ tok_list,
        const int* __restrict__ tiles,
        const float* __restrict__ w_list,
        u16* __restrict__ y_r, float* __restrict__ out) {
    int tt = tiles[blockIdx.x];
    if (tt < 0) return;
    int e = tt >> 16;
    const float* Bd; const u16* interp; const float* wl;
    int m0, seg, n, h0, Kdim;
    if (e < 64) {
        m0 = tt & 0xFFFF; seg = offsets[e]; n = offsets[e + 1] - seg;
        if (n <= 0 || m0 >= n) return;
        h0 = blockIdx.y * 128;
        Bd = dr + (size_t)e * H_DIM * I_DIM;
        interp = inter_r; Kdim = I_DIM; wl = w_list;
    } else {
        h0 = tt & 0xFFFF; m0 = blockIdx.y * BM; seg = 0; n = T_TOK;
        Bd = dsw; interp = inter_s; Kdim = SI_DIM; wl = nullptr;
    }

    __shared__ u16 As[2][BM * BK];    // 2 x 16KB, linear (source-preswizzled)
    __shared__ u16 Bs[2][128 * BK];   // 2 x 16KB, xor-swizzled

    int tid = threadIdx.x;
    int w = tid >> 6, lane = tid & 63;

    const u16* agsrc[4];
    #pragma unroll
    for (int s = 0; s < 4; ++s) {
        int slot = s * 256 + tid;
        int r = slot >> 3, cb = slot & 7;
        int p = m0 + r; if (p >= n) p = n - 1;
        agsrc[s] = interp + (size_t)(seg + p) * Kdim + ((cb ^ (r & 7)) * 8);
    }
    auto gldA = [&](int t, int buf) {
        #pragma unroll
        for (int s = 0; s < 4; ++s)
            gld_lds16(agsrc[s] + t * BK, (u16*)As[buf] + s * 2048 + w * 512);
    };

    // B burst: row br = tid>>1, q = tid&1; 64 contiguous floats per chunk.
    int br = tid >> 1, bq = tid & 1;
    const float* bsrc = Bd + (size_t)(h0 + br) * Kdim + bq * 64;
    int bdst[8];
    #pragma unroll
    for (int m = 0; m < 8; ++m)
        bdst[m] = br * BK + ((m ^ (br & 7)) * 8);
    bool oddgrp = bq != 0;

    f32x4 zero; zero[0] = 0.f; zero[1] = 0.f; zero[2] = 0.f; zero[3] = 0.f;
    f32x4 acc[2][8];
    #pragma unroll
    for (int a = 0; a < 2; ++a)
        #pragma unroll
        for (int b = 0; b < 8; ++b) acc[a][b] = zero;

    f32x4 bB[16];
    auto burst = [&](int C) {
        int k0 = C * 128;
        #pragma unroll
        for (int j = 0; j < 16; ++j)
            bB[j] = *(const f32x4*)(bsrc + k0 + j * 4);
    };
    auto dswE = [&]() {
        if (!oddgrp) {
            #pragma unroll
            for (int m = 0; m < 8; ++m)
                *(ushort8*)(&Bs[0][bdst[m]]) = cvt8(bB[2 * m], bB[2 * m + 1]);
        }
    };
    auto dswO = [&]() {
        if (oddgrp) {
            #pragma unroll
            for (int m = 0; m < 8; ++m)
                *(ushort8*)(&Bs[1][bdst[m]]) = cvt8(bB[2 * m], bB[2 * m + 1]);
        }
    };
    auto mmaStep = [&](int buf) {
        #pragma unroll
        for (int ks = 0; ks < 2; ++ks) {
            short8 a[2];
            #pragma unroll
            for (int fm = 0; fm < 2; ++fm) {
                int row = w * 32 + fm * 16 + (lane & 15);
                int cb = ks * 4 + (lane >> 4);
                a[fm] = *(const short8*)(&As[buf][row * BK + ((cb ^ (row & 7)) * 8)]);
            }
            #pragma unroll
            for (int fn = 0; fn < 8; ++fn) {
                int brow = fn * 16 + (lane & 15);
                int cb = ks * 4 + (lane >> 4);
                short8 b = *(const short8*)(&Bs[buf][brow * BK + ((cb ^ (brow & 7)) * 8)]);
                acc[0][fn] = mfma16(a[0], b, acc[0][fn]);
                acc[1][fn] = mfma16(a[1], b, acc[1][fn]);
            }
        }
    };

    const int NK = Kdim / BK; // 22 or 44, even; K multiple of 128
    gldA(0, 0);
    burst(0);
    dswE(); dswO();
    __syncthreads();
    for (int t = 0; t < NK; t += 2) {
        if (t + 1 < NK) gldA(t + 1, 1);
        if (t > 0) dswO();
        if (t + 2 < NK) burst(t / 2 + 1);
        mmaStep(0);
        __syncthreads();
        if (t + 1 < NK) {
            if (t + 2 < NK) gldA(t + 2, 0);
            if (t + 2 < NK) dswE();
            mmaStep(1);
            __syncthreads();
        }
    }

    int r0 = (lane >> 4) * 4, cc = lane & 15;
    #pragma unroll
    for (int fm = 0; fm < 2; ++fm) {
        #pragma unroll
        for (int r = 0; r < 4; ++r) {
            int p = m0 + w * 32 + fm * 16 + r0 + r;
            if (p < n) {
                if (wl) {
                    float wt = wl[seg + p];
                    size_t ob = (size_t)(seg + p) * H_DIM + h0 + cc;
                    #pragma unroll
                    for (int fn = 0; fn < 8; ++fn)
                        y_r[ob + fn * 16] = f2bf(acc[fm][fn][r] * wt);
                } else {
                    size_t ob = (size_t)p * H_DIM + h0 + cc;
                    #pragma unroll
                    for (int fn = 0; fn < 8; ++fn)
                        out[ob + fn * 16] = acc[fm][fn][r];
                }
            }
        }
    }
}

// ---------------- combine: out[t,:] += sum_k y_r[slot(t,k),:] ----------------
__global__ __launch_bounds__(256) void k_combine(const u16* __restrict__ y_r,
        const int* __restrict__ slot_of, float* __restrict__ out) {
    int t = blockIdx.x;
    int c = threadIdx.x * 8;
    int sl[8];
    #pragma unroll
    for (int k = 0; k < 8; ++k) sl[k] = slot_of[t * 8 + k];
    float s[8];
    f32x4 o0 = *(const f32x4*)(out + (size_t)t * H_DIM + c);
    f32x4 o1 = *(const f32x4*)(out + (size_t)t * H_DIM + c + 4);
    #pragma unroll
    for (int j = 0; j < 4; ++j) { s[j] = o0[j]; s[4 + j] = o1[j]; }
    #pragma unroll
    for (int k = 0; k < 8; ++k) {
        ushort8 v = *(const ushort8*)(y_r + (size_t)sl[k] * H_DIM + c);
        #pragma unroll
        for (int j = 0; j < 8; ++j) s[j] += bf2f(v[j]);
    }
    f32x4 r0, r1;
    #pragma unroll
    for (int j = 0; j < 4; ++j) { r0[j] = s[j]; r1[j] = s[4 + j]; }
    *(f32x4*)(out + (size_t)t * H_DIM + c) = r0;
    *(f32x4*)(out + (size_t)t * H_DIM + c + 4) = r1;
}

extern "C" void kernel_launch(void* const* d_in, const int* in_sizes, int n_in,
                              void* d_out, int out_size, void* d_ws, size_t ws_size,
                              hipStream_t stream) {
    const float* x         = (const float*)d_in[0];
    const float* gate_w    = (const float*)d_in[1];
    const float* e_bias    = (const float*)d_in[2];
    const float* gate_proj = (const float*)d_in[3];
    const float* up_proj   = (const float*)d_in[4];
    const float* down_proj = (const float*)d_in[5];
    const float* sgw       = (const float*)d_in[6];
    const float* suw       = (const float*)d_in[7];
    const float* sdw       = (const float*)d_in[8];
    float* out = (float*)d_out;

    char* ws = (char*)d_ws;
    size_t off = 0;
    auto alloc = [&](size_t bytes) -> char* {
        char* p = ws + off;
        off += (bytes + 255) & ~(size_t)255;
        return p;
    };
    float* logits   = (float*)alloc((size_t)T_TOK * 64 * 4);
    int*   topk_idx = (int*)  alloc((size_t)T_TOK * 8 * 4);
    float* topk_w   = (float*)alloc((size_t)T_TOK * 8 * 4);
    int*   counts   = (int*)  alloc(256);   // [64]
    int*   offsets  = (int*)  alloc(512);   // [65]
    int*   fill     = (int*)  alloc(256);   // [64]
    int*   tiles_gu = (int*)  alloc(MAXT * 4);
    int*   tiles_dn = (int*)  alloc(MAXT * 4);
    int*   tok_list = (int*)  alloc((size_t)T_TOK * 8 * 4);
    float* w_list   = (float*)alloc((size_t)T_TOK * 8 * 4);
    int*   slot_of  = (int*)  alloc((size_t)T_TOK * 8 * 4);
    u16*   xb       = (u16*)  alloc((size_t)T_TOK * H_DIM * 2);
    u16*   inter_r  = (u16*)  alloc((size_t)T_TOK * 8 * I_DIM * 2);
    u16*   inter_s  = (u16*)  alloc((size_t)T_TOK * SI_DIM * 2);
    u16*   y_r      = (u16*)  alloc((size_t)T_TOK * 8 * H_DIM * 2);

    hipMemsetAsync(counts, 0, 1024, stream); // counts + offsets + fill

    k_cvt<<<(T_TOK * H_DIM) / 2048, 256, 0, stream>>>(x, xb);
    k_gate_logits<<<T_TOK / 8, 256, 0, stream>>>(x, gate_w, logits);
    k_topk<<<T_TOK / 256, 256, 0, stream>>>(logits, e_bias, topk_idx, topk_w, counts);
    k_prefix<<<1, 64, 0, stream>>>(counts, offsets, tiles_gu, tiles_dn);
    k_scatter<<<(T_TOK * 8) / 256, 256, 0, stream>>>(topk_idx, topk_w, offsets, fill,
                                                     tok_list, w_list, slot_of);

    // one gateup launch covering routed + shared experts
    k_gateup<<<dim3(MAXT, I_DIM / 64), 256, 0, stream>>>(
        xb, gate_proj, up_proj, sgw, suw, offsets, tok_list, tiles_gu,
        inter_r, inter_s);
    // one down launch; shared path plain-stores out, routed stores y_r partials
    k_down<<<dim3(MAXT, H_DIM / 128), 256, 0, stream>>>(
        inter_r, inter_s, down_proj, sdw, offsets, tok_list, tiles_dn,
        w_list, y_r, out);
    // gather 8 weighted routed partials per token into out
    k_combine<<<T_TOK, 256, 0, stream>>>(y_r, slot_of, out);
}

// Round 21
// 1257.890 us; speedup vs baseline: 1.4012x; 1.4012x over previous
//
#include <hip/hip_runtime.h>

typedef unsigned short u16;
typedef unsigned int u32;
typedef __attribute__((ext_vector_type(8))) short short8;
typedef __attribute__((ext_vector_type(8))) u16 ushort8;
typedef __attribute__((ext_vector_type(4))) float f32x4;
typedef __attribute__((ext_vector_type(4))) u32 u32x4;

#define T_TOK 2048
#define H_DIM 2048
#define NEXP 64
#define I_DIM 1408
#define SI_DIM 2816
#define BM 128
#define BK 64
#define MAXT 512

__device__ __forceinline__ u16 f2bf(float f) {
    u32 u = __builtin_bit_cast(u32, f);
    u32 r = u + 0x7FFFu + ((u >> 16) & 1u);
    return (u16)(r >> 16);
}

__device__ __forceinline__ float bf2f(u16 v) {
    u32 u = ((u32)v) << 16;
    return __builtin_bit_cast(float, u);
}

// HW packed f32->bf16 (RNE) — one VALU op per 2 elements (guide T12 recipe).
__device__ __forceinline__ u32 cvtpk(float lo, float hi) {
    u32 r;
    asm("v_cvt_pk_bf16_f32 %0, %1, %2" : "=v"(r) : "v"(lo), "v"(hi));
    return r;
}

__device__ __forceinline__ ushort8 cvt8(f32x4 a, f32x4 b) {
    u32x4 p;
    p[0] = cvtpk(a[0], a[1]);
    p[1] = cvtpk(a[2], a[3]);
    p[2] = cvtpk(b[0], b[1]);
    p[3] = cvtpk(b[2], b[3]);
    return __builtin_bit_cast(ushort8, p);
}

__device__ __forceinline__ f32x4 mfma16(short8 a, short8 b, f32x4 c) {
    return __builtin_amdgcn_mfma_f32_16x16x32_bf16(a, b, c, 0, 0, 0);
}

__device__ __forceinline__ void gld_lds16(const void* g, void* l) {
    __builtin_amdgcn_global_load_lds(
        (const __attribute__((address_space(1))) void*)(g),
        (__attribute__((address_space(3))) void*)(l), 16, 0, 0);
}

// ---------------- x -> bf16 ----------------
__global__ __launch_bounds__(256) void k_cvt(const float* __restrict__ x, u16* __restrict__ xb) {
    int i = (blockIdx.x * 256 + threadIdx.x) * 8;
    f32x4 v0 = *(const f32x4*)(x + i);
    f32x4 v1 = *(const f32x4*)(x + i + 4);
    *(ushort8*)(xb + i) = cvt8(v0, v1);
}

// ---------------- gating logits: f64 accumulation ----------------
__global__ __launch_bounds__(256) void k_gate_logits(const float* __restrict__ x,
        const float* __restrict__ gw, float* __restrict__ logits) {
    __shared__ float xs[8][65];
    __shared__ float wsh[64][65];
    int tid = threadIdx.x;
    int t0 = blockIdx.x * 8;
    double acc0 = 0.0, acc1 = 0.0;
    int e = tid & 63, tg = tid >> 6; // tg in [0,4)
    for (int k0 = 0; k0 < H_DIM; k0 += 64) {
        #pragma unroll
        for (int s = 0; s < 2; ++s) {
            int idx = s * 256 + tid;
            int r = idx >> 6, k = idx & 63;
            xs[r][k] = x[(size_t)(t0 + r) * H_DIM + k0 + k];
        }
        #pragma unroll
        for (int s = 0; s < 16; ++s) {
            int idx = s * 256 + tid;
            int r = idx >> 6, k = idx & 63;
            wsh[r][k] = gw[(size_t)r * H_DIM + k0 + k];
        }
        __syncthreads();
        #pragma unroll 8
        for (int k = 0; k < 64; ++k) {
            double wv = (double)wsh[e][k];
            acc0 += (double)xs[tg][k] * wv;
            acc1 += (double)xs[tg + 4][k] * wv;
        }
        __syncthreads();
    }
    logits[(size_t)(t0 + tg) * NEXP + e] = (float)acc0;
    logits[(size_t)(t0 + tg + 4) * NEXP + e] = (float)acc1;
}

// ---------------- per-token group-restricted top-k ----------------
__global__ __launch_bounds__(256) void k_topk(const float* __restrict__ logits,
        const float* __restrict__ ebias, int* __restrict__ topk_idx,
        float* __restrict__ topk_w, int* __restrict__ counts) {
    __shared__ float bsh[64];
    if (threadIdx.x < 64) bsh[threadIdx.x] = ebias[threadIdx.x];
    __syncthreads();
    int t = blockIdx.x * 256 + threadIdx.x;
    float sc[64];
    #pragma unroll
    for (int e2 = 0; e2 < 64; ++e2) {
        float lg = logits[(size_t)t * 64 + e2];
        sc[e2] = 1.0f / (1.0f + expf(-lg));
    }
    float gsc[8];
    #pragma unroll
    for (int g = 0; g < 8; ++g) {
        float m1 = -1e30f, m2 = -1e30f;
        #pragma unroll
        for (int j = 0; j < 8; ++j) {
            float v = sc[g * 8 + j] + bsh[g * 8 + j];
            if (v > m1) { m2 = m1; m1 = v; }
            else if (v > m2) { m2 = v; }
        }
        gsc[g] = m1 + m2;
    }
    u32 gmask = 0;
    #pragma unroll
    for (int it = 0; it < 4; ++it) {
        float best = -1e30f; int bi = 0;
        #pragma unroll
        for (int g = 0; g < 8; ++g) {
            bool ok = !((gmask >> g) & 1u);
            if (ok && gsc[g] > best) { best = gsc[g]; bi = g; }
        }
        gmask |= 1u << bi;
    }
    unsigned long long avail = 0ull;
    #pragma unroll
    for (int g = 0; g < 8; ++g)
        if ((gmask >> g) & 1u) avail |= (0xFFull << (g * 8));
    float wsum = 0.f;
    int idx[8]; float wv[8];
    #pragma unroll
    for (int it = 0; it < 8; ++it) {
        float best = -1e30f, bw = 0.f; int bi = 0;
        #pragma unroll
        for (int e2 = 0; e2 < 64; ++e2) {
            bool ok = (avail >> e2) & 1ull;
            float v = sc[e2] + bsh[e2];
            if (ok && v > best) { best = v; bi = e2; bw = sc[e2]; }
        }
        avail &= ~(1ull << bi);
        idx[it] = bi; wv[it] = bw; wsum += bw;
    }
    float scale = 2.5f / (wsum + 1e-20f);
    #pragma unroll
    for (int it = 0; it < 8; ++it) {
        topk_idx[t * 8 + it] = idx[it];
        topk_w[t * 8 + it] = wv[it] * scale;
        atomicAdd(&counts[idx[it]], 1);
    }
}

// ---------------- prefix sum + unified XCD-grouped tile lists ----------------
__global__ void k_prefix(const int* __restrict__ counts, int* __restrict__ offsets,
                         int* __restrict__ tiles_gu, int* __restrict__ tiles_dn) {
    if (threadIdx.x == 0) {
        int run = 0;
        for (int e = 0; e < 64; ++e) { offsets[e] = run; run += counts[e]; }
        offsets[64] = run;
        for (int i = 0; i < MAXT; ++i) { tiles_gu[i] = -1; tiles_dn[i] = -1; }
        int sg[8] = {0,0,0,0,0,0,0,0};
        int sd[8] = {0,0,0,0,0,0,0,0};
        for (int j = 0; j < SI_DIM / 64; ++j) {           // 44 shared gateup panels
            int xcd = j & 7;
            int pos = xcd + 8 * sg[xcd];
            if (pos < MAXT) { tiles_gu[pos] = (64 << 16) | (j * 64); sg[xcd]++; }
        }
        for (int j = 0; j < H_DIM / 128; ++j) {           // 16 shared down panels
            int xcd = j & 7;
            int pos = xcd + 8 * sd[xcd];
            if (pos < MAXT) { tiles_dn[pos] = (64 << 16) | (j * 128); sd[xcd]++; }
        }
        for (int e = 0; e < 64; ++e) {
            int xcd = e & 7;
            int c = counts[e];
            for (int m0 = 0; m0 < c; m0 += BM) {
                int pg = xcd + 8 * sg[xcd];
                if (pg < MAXT) { tiles_gu[pg] = (e << 16) | m0; sg[xcd]++; }
                int pd = xcd + 8 * sd[xcd];
                if (pd < MAXT) { tiles_dn[pd] = (e << 16) | m0; sd[xcd]++; }
            }
        }
    }
}

// ---------------- scatter (t,k) -> per-expert lists + inverse slot map ------
__global__ __launch_bounds__(256) void k_scatter(const int* __restrict__ topk_idx,
        const float* __restrict__ topk_w, const int* __restrict__ offsets,
        int* __restrict__ fill, int* __restrict__ tok_list, float* __restrict__ w_list,
        int* __restrict__ slot_of) {
    int gid = blockIdx.x * 256 + threadIdx.x;
    int t = gid >> 3;
    int e = topk_idx[gid];
    int pos = offsets[e] + atomicAdd(&fill[e], 1);
    tok_list[pos] = t;
    w_list[pos] = topk_w[gid];
    slot_of[gid] = pos;
}

// ---------------- unified gate+up+silu*mul grouped GEMM ----------------
// 128m x 64n(gate+up), BK=64, 4 waves, dbuf LDS, one barrier/K-step.
// A: global_load_lds direct (source-preswizzled, linear LDS), issued one step
// ahead into the other buffer. B: f32->bf16 (v_cvt_pk) depth-2 register staging.
__global__ __launch_bounds__(256, 2) void k_gateup(
        const u16* __restrict__ xb,
        const float* __restrict__ gr, const float* __restrict__ ur,
        const float* __restrict__ gs, const float* __restrict__ us,
        const int* __restrict__ offsets, const int* __restrict__ tok_list,
        const int* __restrict__ tiles,
        u16* __restrict__ inter_r, u16* __restrict__ inter_s) {
    int tt = tiles[blockIdx.x];
    if (tt < 0) return;
    int e = tt >> 16;
    const float *Bg, *Bu; u16* op; const int* tl;
    int m0, seg, n, i0, Irows;
    if (e < 64) {
        m0 = tt & 0xFFFF; seg = offsets[e]; n = offsets[e + 1] - seg;
        if (n <= 0 || m0 >= n) return;
        i0 = blockIdx.y * 64;
        Bg = gr + (size_t)e * I_DIM * H_DIM;
        Bu = ur + (size_t)e * I_DIM * H_DIM;
        op = inter_r; Irows = I_DIM; tl = tok_list;
    } else {
        if (blockIdx.y >= T_TOK / BM) return;
        i0 = tt & 0xFFFF; m0 = blockIdx.y * BM; seg = 0; n = T_TOK;
        Bg = gs; Bu = us;
        op = inter_s; Irows = SI_DIM; tl = nullptr;
    }

    __shared__ u16 As[2][BM * BK];    // 2 x 16KB, linear (source-preswizzled)
    __shared__ u16 Bsg[2][64 * BK];   // 2 x 8KB, xor-swizzled
    __shared__ u16 Bsu[2][64 * BK];   // 2 x 8KB

    int tid = threadIdx.x;
    int w = tid >> 6, lane = tid & 63;

    // A via gld_lds: call s covers slots [s*256 + w*64, +64); lane l -> slot+l.
    const u16* agsrc[4];
    #pragma unroll
    for (int s = 0; s < 4; ++s) {
        int slot = s * 256 + tid;
        int r = slot >> 3, cb = slot & 7;
        int p = m0 + r; if (p >= n) p = n - 1;
        int tok = tl ? tl[seg + p] : p;
        agsrc[s] = xb + (size_t)tok * H_DIM + ((cb ^ (r & 7)) * 8);
    }
    auto gldA = [&](int t, int buf) {
        #pragma unroll
        for (int s = 0; s < 4; ++s)
            gld_lds16(agsrc[s] + t * BK, (u16*)As[buf] + s * 2048 + w * 512);
    };

    const float* bgsrc[2]; const float* busrc[2]; int bdst[2];
    #pragma unroll
    for (int s = 0; s < 2; ++s) {
        int slot = s * 256 + tid;
        int r = slot >> 3, cb = slot & 7;
        bgsrc[s] = Bg + (size_t)(i0 + r) * H_DIM + cb * 8;
        busrc[s] = Bu + (size_t)(i0 + r) * H_DIM + cb * 8;
        bdst[s] = r * BK + ((cb ^ (r & 7)) * 8);
    }

    f32x4 zero; zero[0] = 0.f; zero[1] = 0.f; zero[2] = 0.f; zero[3] = 0.f;
    f32x4 accg[2][4], accu[2][4];
    #pragma unroll
    for (int a = 0; a < 2; ++a)
        #pragma unroll
        for (int b = 0; b < 4; ++b) { accg[a][b] = zero; accu[a][b] = zero; }

    // B depth-2 register stages (named; rule #20)
    f32x4 stG0[2][2], stU0[2][2], stG1[2][2], stU1[2][2];

    auto ldB0 = [&](int t) {
        int k0 = t * BK;
        #pragma unroll
        for (int s = 0; s < 2; ++s) {
            stG0[s][0] = *(const f32x4*)(bgsrc[s] + k0);
            stG0[s][1] = *(const f32x4*)(bgsrc[s] + k0 + 4);
            stU0[s][0] = *(const f32x4*)(busrc[s] + k0);
            stU0[s][1] = *(const f32x4*)(busrc[s] + k0 + 4);
        }
    };
    auto ldB1 = [&](int t) {
        int k0 = t * BK;
        #pragma unroll
        for (int s = 0; s < 2; ++s) {
            stG1[s][0] = *(const f32x4*)(bgsrc[s] + k0);
            stG1[s][1] = *(const f32x4*)(bgsrc[s] + k0 + 4);
            stU1[s][0] = *(const f32x4*)(busrc[s] + k0);
            stU1[s][1] = *(const f32x4*)(busrc[s] + k0 + 4);
        }
    };
    auto dswB0 = [&]() {
        #pragma unroll
        for (int s = 0; s < 2; ++s) {
            *(ushort8*)(&Bsg[0][bdst[s]]) = cvt8(stG0[s][0], stG0[s][1]);
            *(ushort8*)(&Bsu[0][bdst[s]]) = cvt8(stU0[s][0], stU0[s][1]);
        }
    };
    auto dswB1 = [&]() {
        #pragma unroll
        for (int s = 0; s < 2; ++s) {
            *(ushort8*)(&Bsg[1][bdst[s]]) = cvt8(stG1[s][0], stG1[s][1]);
            *(ushort8*)(&Bsu[1][bdst[s]]) = cvt8(stU1[s][0], stU1[s][1]);
        }
    };
    auto mmaStep = [&](int buf) {
        #pragma unroll
        for (int ks = 0; ks < 2; ++ks) {
            short8 a[2];
            #pragma unroll
            for (int fm = 0; fm < 2; ++fm) {
                int row = w * 32 + fm * 16 + (lane & 15);
                int cb = ks * 4 + (lane >> 4);
                a[fm] = *(const short8*)(&As[buf][row * BK + ((cb ^ (row & 7)) * 8)]);
            }
            #pragma unroll
            for (int fn = 0; fn < 4; ++fn) {
                int brow = fn * 16 + (lane & 15);
                int cb = ks * 4 + (lane >> 4);
                int boff = brow * BK + ((cb ^ (brow & 7)) * 8);
                short8 bg = *(const short8*)(&Bsg[buf][boff]);
                short8 bu = *(const short8*)(&Bsu[buf][boff]);
                accg[0][fn] = mfma16(a[0], bg, accg[0][fn]);
                accg[1][fn] = mfma16(a[1], bg, accg[1][fn]);
                accu[0][fn] = mfma16(a[0], bu, accu[0][fn]);
                accu[1][fn] = mfma16(a[1], bu, accu[1][fn]);
            }
        }
    };

    const int NK = H_DIM / BK; // 32, even
    gldA(0, 0);
    ldB0(0); dswB0();
    ldB1(1);
    __syncthreads();
    for (int t = 0; t < NK; t += 2) {
        // even step: reads buf0 (tile t)
        if (t + 1 < NK) gldA(t + 1, 1);
        if (t + 2 < NK) ldB0(t + 2);
        mmaStep(0);
        if (t + 1 < NK) dswB1();
        __syncthreads();
        if (t + 1 < NK) {
            // odd step: reads buf1 (tile t+1)
            if (t + 2 < NK) gldA(t + 2, 0);
            if (t + 3 < NK) ldB1(t + 3);
            mmaStep(1);
            if (t + 2 < NK) dswB0();
            __syncthreads();
        }
    }

    int r0 = (lane >> 4) * 4, cc = lane & 15;
    #pragma unroll
    for (int fm = 0; fm < 2; ++fm) {
        #pragma unroll
        for (int r = 0; r < 4; ++r) {
            int p = m0 + w * 32 + fm * 16 + r0 + r;
            if (p < n) {
                size_t rowb = (size_t)(seg + p) * Irows + i0;
                #pragma unroll
                for (int fn = 0; fn < 4; ++fn) {
                    float g = accg[fm][fn][r], u = accu[fm][fn][r];
                    float val = g / (1.0f + expf(-g)) * u;
                    op[rowb + fn * 16 + cc] = f2bf(val);
                }
            }
        }
    }
}

// ---------------- unified down-proj grouped GEMM (NO atomics) ----------------
// 128m x 128n, BK=64, 4 waves. A via gld_lds (one step ahead), B depth-2 regs.
// Routed: weighted bf16 partials to y_r. Shared: plain f32 store to out.
__global__ __launch_bounds__(256, 2) void k_down(
        const u16* __restrict__ inter_r, const u16* __restrict__ inter_s,
        const float* __restrict__ dr, const float* __restrict__ dsw,
        const int* __restrict__ offsets, const int* __restrict__ tok_list,
        const int* __restrict__ tiles,
        const float* __restrict__ w_list,
        u16* __restrict__ y_r, float* __restrict__ out) {
    int tt = tiles[blockIdx.x];
    if (tt < 0) return;
    int e = tt >> 16;
    const float* Bd; const u16* interp; const float* wl;
    int m0, seg, n, h0, Kdim;
    if (e < 64) {
        m0 = tt & 0xFFFF; seg = offsets[e]; n = offsets[e + 1] - seg;
        if (n <= 0 || m0 >= n) return;
        h0 = blockIdx.y * 128;
        Bd = dr + (size_t)e * H_DIM * I_DIM;
        interp = inter_r; Kdim = I_DIM; wl = w_list;
    } else {
        h0 = tt & 0xFFFF; m0 = blockIdx.y * BM; seg = 0; n = T_TOK;
        Bd = dsw; interp = inter_s; Kdim = SI_DIM; wl = nullptr;
    }

    __shared__ u16 As[2][BM * BK];    // 2 x 16KB, linear (source-preswizzled)
    __shared__ u16 Bs[2][128 * BK];   // 2 x 16KB, xor-swizzled

    int tid = threadIdx.x;
    int w = tid >> 6, lane = tid & 63;

    const u16* agsrc[4];
    #pragma unroll
    for (int s = 0; s < 4; ++s) {
        int slot = s * 256 + tid;
        int r = slot >> 3, cb = slot & 7;
        int p = m0 + r; if (p >= n) p = n - 1;
        agsrc[s] = interp + (size_t)(seg + p) * Kdim + ((cb ^ (r & 7)) * 8);
    }
    auto gldA = [&](int t, int buf) {
        #pragma unroll
        for (int s = 0; s < 4; ++s)
            gld_lds16(agsrc[s] + t * BK, (u16*)As[buf] + s * 2048 + w * 512);
    };

    const float* bsrc[4]; int bdst[4];
    #pragma unroll
    for (int s = 0; s < 4; ++s) {
        int slot = s * 256 + tid;
        int r = slot >> 3, cb = slot & 7;
        bsrc[s] = Bd + (size_t)(h0 + r) * Kdim + cb * 8;
        bdst[s] = r * BK + ((cb ^ (r & 7)) * 8);
    }

    f32x4 zero; zero[0] = 0.f; zero[1] = 0.f; zero[2] = 0.f; zero[3] = 0.f;
    f32x4 acc[2][8];
    #pragma unroll
    for (int a = 0; a < 2; ++a)
        #pragma unroll
        for (int b = 0; b < 8; ++b) acc[a][b] = zero;

    f32x4 stB0[4][2], stB1[4][2];

    auto ldB0 = [&](int t) {
        int k0 = t * BK;
        #pragma unroll
        for (int s = 0; s < 4; ++s) {
            stB0[s][0] = *(const f32x4*)(bsrc[s] + k0);
            stB0[s][1] = *(const f32x4*)(bsrc[s] + k0 + 4);
        }
    };
    auto ldB1 = [&](int t) {
        int k0 = t * BK;
        #pragma unroll
        for (int s = 0; s < 4; ++s) {
            stB1[s][0] = *(const f32x4*)(bsrc[s] + k0);
            stB1[s][1] = *(const f32x4*)(bsrc[s] + k0 + 4);
        }
    };
    auto dswB0 = [&]() {
        #pragma unroll
        for (int s = 0; s < 4; ++s)
            *(ushort8*)(&Bs[0][bdst[s]]) = cvt8(stB0[s][0], stB0[s][1]);
    };
    auto dswB1 = [&]() {
        #pragma unroll
        for (int s = 0; s < 4; ++s)
            *(ushort8*)(&Bs[1][bdst[s]]) = cvt8(stB1[s][0], stB1[s][1]);
    };
    auto mmaStep = [&](int buf) {
        #pragma unroll
        for (int ks = 0; ks < 2; ++ks) {
            short8 a[2];
            #pragma unroll
            for (int fm = 0; fm < 2; ++fm) {
                int row = w * 32 + fm * 16 + (lane & 15);
                int cb = ks * 4 + (lane >> 4);
                a[fm] = *(const short8*)(&As[buf][row * BK + ((cb ^ (row & 7)) * 8)]);
            }
            #pragma unroll
            for (int fn = 0; fn < 8; ++fn) {
                int brow = fn * 16 + (lane & 15);
                int cb = ks * 4 + (lane >> 4);
                short8 b = *(const short8*)(&Bs[buf][brow * BK + ((cb ^ (brow & 7)) * 8)]);
                acc[0][fn] = mfma16(a[0], b, acc[0][fn]);
                acc[1][fn] = mfma16(a[1], b, acc[1][fn]);
            }
        }
    };

    const int NK = Kdim / BK; // 22 or 44, even
    gldA(0, 0);
    ldB0(0); dswB0();
    ldB1(1);
    __syncthreads();
    for (int t = 0; t < NK; t += 2) {
        if (t + 1 < NK) gldA(t + 1, 1);
        if (t + 2 < NK) ldB0(t + 2);
        mmaStep(0);
        if (t + 1 < NK) dswB1();
        __syncthreads();
        if (t + 1 < NK) {
            if (t + 2 < NK) gldA(t + 2, 0);
            if (t + 3 < NK) ldB1(t + 3);
            mmaStep(1);
            if (t + 2 < NK) dswB0();
            __syncthreads();
        }
    }

    int r0 = (lane >> 4) * 4, cc = lane & 15;
    #pragma unroll
    for (int fm = 0; fm < 2; ++fm) {
        #pragma unroll
        for (int r = 0; r < 4; ++r) {
            int p = m0 + w * 32 + fm * 16 + r0 + r;
            if (p < n) {
                if (wl) {
                    float wt = wl[seg + p];
                    size_t ob = (size_t)(seg + p) * H_DIM + h0 + cc;
                    #pragma unroll
                    for (int fn = 0; fn < 8; ++fn)
                        y_r[ob + fn * 16] = f2bf(acc[fm][fn][r] * wt);
                } else {
                    size_t ob = (size_t)p * H_DIM + h0 + cc;
                    #pragma unroll
                    for (int fn = 0; fn < 8; ++fn)
                        out[ob + fn * 16] = acc[fm][fn][r];
                }
            }
        }
    }
}

// ---------------- combine: out[t,:] += sum_k y_r[slot(t,k),:] ----------------
__global__ __launch_bounds__(256) void k_combine(const u16* __restrict__ y_r,
        const int* __restrict__ slot_of, float* __restrict__ out) {
    int t = blockIdx.x;
    int c = threadIdx.x * 8;
    int sl[8];
    #pragma unroll
    for (int k = 0; k < 8; ++k) sl[k] = slot_of[t * 8 + k];
    float s[8];
    f32x4 o0 = *(const f32x4*)(out + (size_t)t * H_DIM + c);
    f32x4 o1 = *(const f32x4*)(out + (size_t)t * H_DIM + c + 4);
    #pragma unroll
    for (int j = 0; j < 4; ++j) { s[j] = o0[j]; s[4 + j] = o1[j]; }
    #pragma unroll
    for (int k = 0; k < 8; ++k) {
        ushort8 v = *(const ushort8*)(y_r + (size_t)sl[k] * H_DIM + c);
        #pragma unroll
        for (int j = 0; j < 8; ++j) s[j] += bf2f(v[j]);
    }
    f32x4 r0, r1;
    #pragma unroll
    for (int j = 0; j < 4; ++j) { r0[j] = s[j]; r1[j] = s[4 + j]; }
    *(f32x4*)(out + (size_t)t * H_DIM + c) = r0;
    *(f32x4*)(out + (size_t)t * H_DIM + c + 4) = r1;
}

extern "C" void kernel_launch(void* const* d_in, const int* in_sizes, int n_in,
                              void* d_out, int out_size, void* d_ws, size_t ws_size,
                              hipStream_t stream) {
    const float* x         = (const float*)d_in[0];
    const float* gate_w    = (const float*)d_in[1];
    const float* e_bias    = (const float*)d_in[2];
    const float* gate_proj = (const float*)d_in[3];
    const float* up_proj   = (const float*)d_in[4];
    const float* down_proj = (const float*)d_in[5];
    const float* sgw       = (const float*)d_in[6];
    const float* suw       = (const float*)d_in[7];
    const float* sdw       = (const float*)d_in[8];
    float* out = (float*)d_out;

    char* ws = (char*)d_ws;
    size_t off = 0;
    auto alloc = [&](size_t bytes) -> char* {
        char* p = ws + off;
        off += (bytes + 255) & ~(size_t)255;
        return p;
    };
    float* logits   = (float*)alloc((size_t)T_TOK * 64 * 4);
    int*   topk_idx = (int*)  alloc((size_t)T_TOK * 8 * 4);
    float* topk_w   = (float*)alloc((size_t)T_TOK * 8 * 4);
    int*   counts   = (int*)  alloc(256);   // [64]
    int*   offsets  = (int*)  alloc(512);   // [65]
    int*   fill     = (int*)  alloc(256);   // [64]
    int*   tiles_gu = (int*)  alloc(MAXT * 4);
    int*   tiles_dn = (int*)  alloc(MAXT * 4);
    int*   tok_list = (int*)  alloc((size_t)T_TOK * 8 * 4);
    float* w_list   = (float*)alloc((size_t)T_TOK * 8 * 4);
    int*   slot_of  = (int*)  alloc((size_t)T_TOK * 8 * 4);
    u16*   xb       = (u16*)  alloc((size_t)T_TOK * H_DIM * 2);
    u16*   inter_r  = (u16*)  alloc((size_t)T_TOK * 8 * I_DIM * 2);
    u16*   inter_s  = (u16*)  alloc((size_t)T_TOK * SI_DIM * 2);
    u16*   y_r      = (u16*)  alloc((size_t)T_TOK * 8 * H_DIM * 2);

    hipMemsetAsync(counts, 0, 1024, stream); // counts + offsets + fill

    k_cvt<<<(T_TOK * H_DIM) / 2048, 256, 0, stream>>>(x, xb);
    k_gate_logits<<<T_TOK / 8, 256, 0, stream>>>(x, gate_w, logits);
    k_topk<<<T_TOK / 256, 256, 0, stream>>>(logits, e_bias, topk_idx, topk_w, counts);
    k_prefix<<<1, 64, 0, stream>>>(counts, offsets, tiles_gu, tiles_dn);
    k_scatter<<<(T_TOK * 8) / 256, 256, 0, stream>>>(topk_idx, topk_w, offsets, fill,
                                                     tok_list, w_list, slot_of);

    // one gateup launch covering routed + shared experts
    k_gateup<<<dim3(MAXT, I_DIM / 64), 256, 0, stream>>>(
        xb, gate_proj, up_proj, sgw, suw, offsets, tok_list, tiles_gu,
        inter_r, inter_s);
    // one down launch; shared path plain-stores out, routed stores y_r partials
    k_down<<<dim3(MAXT, H_DIM / 128), 256, 0, stream>>>(
        inter_r, inter_s, down_proj, sdw, offsets, tok_list, tiles_dn,
        w_list, y_r, out);
    // gather 8 weighted routed partials per token into out
    k_combine<<<T_TOK, 256, 0, stream>>>(y_r, slot_of, out);
}

// Round 22
// 1086.981 us; speedup vs baseline: 1.6215x; 1.1572x over previous
//
#include <hip/hip_runtime.h>

typedef unsigned short u16;
typedef unsigned int u32;
typedef __attribute__((ext_vector_type(8))) short short8;
typedef __attribute__((ext_vector_type(8))) u16 ushort8;
typedef __attribute__((ext_vector_type(4))) float f32x4;
typedef __attribute__((ext_vector_type(4))) u32 u32x4;

#define T_TOK 2048
#define H_DIM 2048
#define NEXP 64
#define I_DIM 1408
#define SI_DIM 2816
#define BM 128
#define BK 64
#define MAXT 512

__device__ __forceinline__ u16 f2bf(float f) {
    u32 u = __builtin_bit_cast(u32, f);
    u32 r = u + 0x7FFFu + ((u >> 16) & 1u);
    return (u16)(r >> 16);
}

__device__ __forceinline__ float bf2f(u16 v) {
    u32 u = ((u32)v) << 16;
    return __builtin_bit_cast(float, u);
}

// HW packed f32->bf16 (RNE) — one VALU op per 2 elements (guide T12 recipe).
__device__ __forceinline__ u32 cvtpk(float lo, float hi) {
    u32 r;
    asm("v_cvt_pk_bf16_f32 %0, %1, %2" : "=v"(r) : "v"(lo), "v"(hi));
    return r;
}

__device__ __forceinline__ ushort8 cvt8(f32x4 a, f32x4 b) {
    u32x4 p;
    p[0] = cvtpk(a[0], a[1]);
    p[1] = cvtpk(a[2], a[3]);
    p[2] = cvtpk(b[0], b[1]);
    p[3] = cvtpk(b[2], b[3]);
    return __builtin_bit_cast(ushort8, p);
}

__device__ __forceinline__ f32x4 mfma16(short8 a, short8 b, f32x4 c) {
    return __builtin_amdgcn_mfma_f32_16x16x32_bf16(a, b, c, 0, 0, 0);
}

__device__ __forceinline__ void gld_lds16(const void* g, void* l) {
    __builtin_amdgcn_global_load_lds(
        (const __attribute__((address_space(1))) void*)(g),
        (__attribute__((address_space(3))) void*)(l), 16, 0, 0);
}

// ---------------- x -> bf16 ----------------
__global__ __launch_bounds__(256) void k_cvt(const float* __restrict__ x, u16* __restrict__ xb) {
    int i = (blockIdx.x * 256 + threadIdx.x) * 8;
    f32x4 v0 = *(const f32x4*)(x + i);
    f32x4 v1 = *(const f32x4*)(x + i + 4);
    *(ushort8*)(xb + i) = cvt8(v0, v1);
}

// ---------------- gating: f64-accurate logits + in-block top-k ----------------
// 8 tokens/block. Logits stay in LDS; threads 0..7 run the serial
// group-restricted top-k (identical math to the reference path).
__global__ __launch_bounds__(256) void k_gate_fused(const float* __restrict__ x,
        const float* __restrict__ gw, const float* __restrict__ ebias,
        int* __restrict__ topk_idx, float* __restrict__ topk_w,
        int* __restrict__ counts) {
    __shared__ float xs[8][65];
    __shared__ float wsh[64][65];
    __shared__ float lg[8][65];     // logits (padded)
    __shared__ float bsh[64];
    int tid = threadIdx.x;
    int t0 = blockIdx.x * 8;
    if (tid < 64) bsh[tid] = ebias[tid];
    double acc0 = 0.0, acc1 = 0.0;
    int e = tid & 63, tg = tid >> 6; // tg in [0,4)
    for (int k0 = 0; k0 < H_DIM; k0 += 64) {
        #pragma unroll
        for (int s = 0; s < 2; ++s) {
            int idx = s * 256 + tid;
            int r = idx >> 6, k = idx & 63;
            xs[r][k] = x[(size_t)(t0 + r) * H_DIM + k0 + k];
        }
        #pragma unroll
        for (int s = 0; s < 16; ++s) {
            int idx = s * 256 + tid;
            int r = idx >> 6, k = idx & 63;
            wsh[r][k] = gw[(size_t)r * H_DIM + k0 + k];
        }
        __syncthreads();
        #pragma unroll 8
        for (int k = 0; k < 64; ++k) {
            double wv = (double)wsh[e][k];
            acc0 += (double)xs[tg][k] * wv;
            acc1 += (double)xs[tg + 4][k] * wv;
        }
        __syncthreads();
    }
    lg[tg][e] = (float)acc0;
    lg[tg + 4][e] = (float)acc1;
    __syncthreads();

    if (tid < 8) {
        int t = t0 + tid;
        float sc[64];
        #pragma unroll
        for (int e2 = 0; e2 < 64; ++e2)
            sc[e2] = 1.0f / (1.0f + expf(-lg[tid][e2]));
        float gsc[8];
        #pragma unroll
        for (int g = 0; g < 8; ++g) {
            float m1 = -1e30f, m2 = -1e30f;
            #pragma unroll
            for (int j = 0; j < 8; ++j) {
                float v = sc[g * 8 + j] + bsh[g * 8 + j];
                if (v > m1) { m2 = m1; m1 = v; }
                else if (v > m2) { m2 = v; }
            }
            gsc[g] = m1 + m2;
        }
        u32 gmask = 0;
        #pragma unroll
        for (int it = 0; it < 4; ++it) {
            float best = -1e30f; int bi = 0;
            #pragma unroll
            for (int g = 0; g < 8; ++g) {
                bool ok = !((gmask >> g) & 1u);
                if (ok && gsc[g] > best) { best = gsc[g]; bi = g; }
            }
            gmask |= 1u << bi;
        }
        unsigned long long avail = 0ull;
        #pragma unroll
        for (int g = 0; g < 8; ++g)
            if ((gmask >> g) & 1u) avail |= (0xFFull << (g * 8));
        float wsum = 0.f;
        int idx[8]; float wv[8];
        #pragma unroll
        for (int it = 0; it < 8; ++it) {
            float best = -1e30f, bw = 0.f; int bi = 0;
            #pragma unroll
            for (int e2 = 0; e2 < 64; ++e2) {
                bool ok = (avail >> e2) & 1ull;
                float v = sc[e2] + bsh[e2];
                if (ok && v > best) { best = v; bi = e2; bw = sc[e2]; }
            }
            avail &= ~(1ull << bi);
            idx[it] = bi; wv[it] = bw; wsum += bw;
        }
        float scale = 2.5f / (wsum + 1e-20f);
        #pragma unroll
        for (int it = 0; it < 8; ++it) {
            topk_idx[t * 8 + it] = idx[it];
            topk_w[t * 8 + it] = wv[it] * scale;
            atomicAdd(&counts[idx[it]], 1);
        }
    }
}

// ---------------- parallel prefix + XCD-grouped tile lists (1 wave) ---------
// Same layout as the serial version: shared panel j at (j&7)+8*(j>>3);
// expert tiles follow in expert order within each XCD class.
__global__ __launch_bounds__(64) void k_prefix(const int* __restrict__ counts,
        int* __restrict__ offsets, int* __restrict__ tiles_gu, int* __restrict__ tiles_dn) {
    int e = threadIdx.x;            // one wave of 64
    // init tile lists (disjoint coverage; drained by __syncthreads below)
    #pragma unroll
    for (int j = 0; j < MAXT / 64; ++j) {
        tiles_gu[e + j * 64] = -1;
        tiles_dn[e + j * 64] = -1;
    }
    __syncthreads();

    int c = counts[e];
    // inclusive scan over all 64 lanes -> offsets
    int sum = c;
    #pragma unroll
    for (int d = 1; d < 64; d <<= 1) {
        int v = __shfl_up(sum, d, 64);
        if (e >= d) sum += v;
    }
    offsets[e] = sum - c;
    if (e == 63) offsets[64] = sum;

    // per-xcd (stride-8) exclusive scan of tile counts
    int nt = (c + BM - 1) / BM;
    int ssum = nt;
    #pragma unroll
    for (int d = 8; d < 64; d <<= 1) {
        int v = __shfl_up(ssum, d, 64);
        if (e >= d) ssum += v;
    }
    int slotbase = ssum - nt;
    int xcd = e & 7;
    // shared-panel counts ahead of experts in each xcd class
    int shg = (43 - xcd) / 8 + 1;   // 44 gateup panels: xcd<4 -> 6, else 5
    int shd = 2;                    // 16 down panels: 2 per xcd

    // shared panel entries (threads 0..43 / 0..15)
    if (e < SI_DIM / 64) tiles_gu[(e & 7) + 8 * (e >> 3)] = (64 << 16) | (e * 64);
    if (e < H_DIM / 128) tiles_dn[(e & 7) + 8 * (e >> 3)] = (64 << 16) | (e * 128);

    // expert tiles
    for (int i = 0; i < nt; ++i) {
        int m0 = i * BM;
        int pg = xcd + 8 * (shg + slotbase + i);
        if (pg < MAXT) tiles_gu[pg] = (e << 16) | m0;
        int pd = xcd + 8 * (shd + slotbase + i);
        if (pd < MAXT) tiles_dn[pd] = (e << 16) | m0;
    }
}

// ---------------- scatter (t,k) -> per-expert lists + inverse slot map ------
__global__ __launch_bounds__(256) void k_scatter(const int* __restrict__ topk_idx,
        const float* __restrict__ topk_w, const int* __restrict__ offsets,
        int* __restrict__ fill, int* __restrict__ tok_list, float* __restrict__ w_list,
        int* __restrict__ slot_of) {
    int gid = blockIdx.x * 256 + threadIdx.x;
    int t = gid >> 3;
    int e = topk_idx[gid];
    int pos = offsets[e] + atomicAdd(&fill[e], 1);
    tok_list[pos] = t;
    w_list[pos] = topk_w[gid];
    slot_of[gid] = pos;
}

// ---------------- unified gate+up+silu*mul grouped GEMM ----------------
// 128m x 64n(gate+up), BK=64, 4 waves, dbuf LDS, one barrier/K-step.
// A: global_load_lds direct (source-preswizzled, linear LDS), issued one step
// ahead into the other buffer. B: f32->bf16 (v_cvt_pk) depth-2 register staging.
__global__ __launch_bounds__(256, 2) void k_gateup(
        const u16* __restrict__ xb,
        const float* __restrict__ gr, const float* __restrict__ ur,
        const float* __restrict__ gs, const float* __restrict__ us,
        const int* __restrict__ offsets, const int* __restrict__ tok_list,
        const int* __restrict__ tiles,
        u16* __restrict__ inter_r, u16* __restrict__ inter_s) {
    int tt = tiles[blockIdx.x];
    if (tt < 0) return;
    int e = tt >> 16;
    const float *Bg, *Bu; u16* op; const int* tl;
    int m0, seg, n, i0, Irows;
    if (e < 64) {
        m0 = tt & 0xFFFF; seg = offsets[e]; n = offsets[e + 1] - seg;
        if (n <= 0 || m0 >= n) return;
        i0 = blockIdx.y * 64;
        Bg = gr + (size_t)e * I_DIM * H_DIM;
        Bu = ur + (size_t)e * I_DIM * H_DIM;
        op = inter_r; Irows = I_DIM; tl = tok_list;
    } else {
        if (blockIdx.y >= T_TOK / BM) return;
        i0 = tt & 0xFFFF; m0 = blockIdx.y * BM; seg = 0; n = T_TOK;
        Bg = gs; Bu = us;
        op = inter_s; Irows = SI_DIM; tl = nullptr;
    }

    __shared__ u16 As[2][BM * BK];    // 2 x 16KB, linear (source-preswizzled)
    __shared__ u16 Bsg[2][64 * BK];   // 2 x 8KB, xor-swizzled
    __shared__ u16 Bsu[2][64 * BK];   // 2 x 8KB

    int tid = threadIdx.x;
    int w = tid >> 6, lane = tid & 63;

    // A via gld_lds: call s covers slots [s*256 + w*64, +64); lane l -> slot+l.
    const u16* agsrc[4];
    #pragma unroll
    for (int s = 0; s < 4; ++s) {
        int slot = s * 256 + tid;
        int r = slot >> 3, cb = slot & 7;
        int p = m0 + r; if (p >= n) p = n - 1;
        int tok = tl ? tl[seg + p] : p;
        agsrc[s] = xb + (size_t)tok * H_DIM + ((cb ^ (r & 7)) * 8);
    }
    auto gldA = [&](int t, int buf) {
        #pragma unroll
        for (int s = 0; s < 4; ++s)
            gld_lds16(agsrc[s] + t * BK, (u16*)As[buf] + s * 2048 + w * 512);
    };

    const float* bgsrc[2]; const float* busrc[2]; int bdst[2];
    #pragma unroll
    for (int s = 0; s < 2; ++s) {
        int slot = s * 256 + tid;
        int r = slot >> 3, cb = slot & 7;
        bgsrc[s] = Bg + (size_t)(i0 + r) * H_DIM + cb * 8;
        busrc[s] = Bu + (size_t)(i0 + r) * H_DIM + cb * 8;
        bdst[s] = r * BK + ((cb ^ (r & 7)) * 8);
    }

    f32x4 zero; zero[0] = 0.f; zero[1] = 0.f; zero[2] = 0.f; zero[3] = 0.f;
    f32x4 accg[2][4], accu[2][4];
    #pragma unroll
    for (int a = 0; a < 2; ++a)
        #pragma unroll
        for (int b = 0; b < 4; ++b) { accg[a][b] = zero; accu[a][b] = zero; }

    // B depth-2 register stages (named; rule #20)
    f32x4 stG0[2][2], stU0[2][2], stG1[2][2], stU1[2][2];

    auto ldB0 = [&](int t) {
        int k0 = t * BK;
        #pragma unroll
        for (int s = 0; s < 2; ++s) {
            stG0[s][0] = *(const f32x4*)(bgsrc[s] + k0);
            stG0[s][1] = *(const f32x4*)(bgsrc[s] + k0 + 4);
            stU0[s][0] = *(const f32x4*)(busrc[s] + k0);
            stU0[s][1] = *(const f32x4*)(busrc[s] + k0 + 4);
        }
    };
    auto ldB1 = [&](int t) {
        int k0 = t * BK;
        #pragma unroll
        for (int s = 0; s < 2; ++s) {
            stG1[s][0] = *(const f32x4*)(bgsrc[s] + k0);
            stG1[s][1] = *(const f32x4*)(bgsrc[s] + k0 + 4);
            stU1[s][0] = *(const f32x4*)(busrc[s] + k0);
            stU1[s][1] = *(const f32x4*)(busrc[s] + k0 + 4);
        }
    };
    auto dswB0 = [&]() {
        #pragma unroll
        for (int s = 0; s < 2; ++s) {
            *(ushort8*)(&Bsg[0][bdst[s]]) = cvt8(stG0[s][0], stG0[s][1]);
            *(ushort8*)(&Bsu[0][bdst[s]]) = cvt8(stU0[s][0], stU0[s][1]);
        }
    };
    auto dswB1 = [&]() {
        #pragma unroll
        for (int s = 0; s < 2; ++s) {
            *(ushort8*)(&Bsg[1][bdst[s]]) = cvt8(stG1[s][0], stG1[s][1]);
            *(ushort8*)(&Bsu[1][bdst[s]]) = cvt8(stU1[s][0], stU1[s][1]);
        }
    };
    auto mmaStep = [&](int buf) {
        #pragma unroll
        for (int ks = 0; ks < 2; ++ks) {
            short8 a[2];
            #pragma unroll
            for (int fm = 0; fm < 2; ++fm) {
                int row = w * 32 + fm * 16 + (lane & 15);
                int cb = ks * 4 + (lane >> 4);
                a[fm] = *(const short8*)(&As[buf][row * BK + ((cb ^ (row & 7)) * 8)]);
            }
            #pragma unroll
            for (int fn = 0; fn < 4; ++fn) {
                int brow = fn * 16 + (lane & 15);
                int cb = ks * 4 + (lane >> 4);
                int boff = brow * BK + ((cb ^ (brow & 7)) * 8);
                short8 bg = *(const short8*)(&Bsg[buf][boff]);
                short8 bu = *(const short8*)(&Bsu[buf][boff]);
                accg[0][fn] = mfma16(a[0], bg, accg[0][fn]);
                accg[1][fn] = mfma16(a[1], bg, accg[1][fn]);
                accu[0][fn] = mfma16(a[0], bu, accu[0][fn]);
                accu[1][fn] = mfma16(a[1], bu, accu[1][fn]);
            }
        }
    };

    const int NK = H_DIM / BK; // 32, even
    gldA(0, 0);
    ldB0(0); dswB0();
    ldB1(1);
    __syncthreads();
    for (int t = 0; t < NK; t += 2) {
        // even step: reads buf0 (tile t)
        if (t + 1 < NK) gldA(t + 1, 1);
        if (t + 2 < NK) ldB0(t + 2);
        mmaStep(0);
        if (t + 1 < NK) dswB1();
        __syncthreads();
        if (t + 1 < NK) {
            // odd step: reads buf1 (tile t+1)
            if (t + 2 < NK) gldA(t + 2, 0);
            if (t + 3 < NK) ldB1(t + 3);
            mmaStep(1);
            if (t + 2 < NK) dswB0();
            __syncthreads();
        }
    }

    int r0 = (lane >> 4) * 4, cc = lane & 15;
    #pragma unroll
    for (int fm = 0; fm < 2; ++fm) {
        #pragma unroll
        for (int r = 0; r < 4; ++r) {
            int p = m0 + w * 32 + fm * 16 + r0 + r;
            if (p < n) {
                size_t rowb = (size_t)(seg + p) * Irows + i0;
                #pragma unroll
                for (int fn = 0; fn < 4; ++fn) {
                    float g = accg[fm][fn][r], u = accu[fm][fn][r];
                    float val = g / (1.0f + expf(-g)) * u;
                    op[rowb + fn * 16 + cc] = f2bf(val);
                }
            }
        }
    }
}

// ---------------- unified down-proj grouped GEMM (NO atomics) ----------------
// 128m x 128n, BK=64, 4 waves. A via gld_lds (one step ahead), B depth-2 regs.
// Routed: weighted bf16 partials to y_r. Shared: plain f32 store to out.
__global__ __launch_bounds__(256, 2) void k_down(
        const u16* __restrict__ inter_r, const u16* __restrict__ inter_s,
        const float* __restrict__ dr, const float* __restrict__ dsw,
        const int* __restrict__ offsets, const int* __restrict__ tok_list,
        const int* __restrict__ tiles,
        const float* __restrict__ w_list,
        u16* __restrict__ y_r, float* __restrict__ out) {
    int tt = tiles[blockIdx.x];
    if (tt < 0) return;
    int e = tt >> 16;
    const float* Bd; const u16* interp; const float* wl;
    int m0, seg, n, h0, Kdim;
    if (e < 64) {
        m0 = tt & 0xFFFF; seg = offsets[e]; n = offsets[e + 1] - seg;
        if (n <= 0 || m0 >= n) return;
        h0 = blockIdx.y * 128;
        Bd = dr + (size_t)e * H_DIM * I_DIM;
        interp = inter_r; Kdim = I_DIM; wl = w_list;
    } else {
        h0 = tt & 0xFFFF; m0 = blockIdx.y * BM; seg = 0; n = T_TOK;
        Bd = dsw; interp = inter_s; Kdim = SI_DIM; wl = nullptr;
    }

    __shared__ u16 As[2][BM * BK];    // 2 x 16KB, linear (source-preswizzled)
    __shared__ u16 Bs[2][128 * BK];   // 2 x 16KB, xor-swizzled

    int tid = threadIdx.x;
    int w = tid >> 6, lane = tid & 63;

    const u16* agsrc[4];
    #pragma unroll
    for (int s = 0; s < 4; ++s) {
        int slot = s * 256 + tid;
        int r = slot >> 3, cb = slot & 7;
        int p = m0 + r; if (p >= n) p = n - 1;
        agsrc[s] = interp + (size_t)(seg + p) * Kdim + ((cb ^ (r & 7)) * 8);
    }
    auto gldA = [&](int t, int buf) {
        #pragma unroll
        for (int s = 0; s < 4; ++s)
            gld_lds16(agsrc[s] + t * BK, (u16*)As[buf] + s * 2048 + w * 512);
    };

    const float* bsrc[4]; int bdst[4];
    #pragma unroll
    for (int s = 0; s < 4; ++s) {
        int slot = s * 256 + tid;
        int r = slot >> 3, cb = slot & 7;
        bsrc[s] = Bd + (size_t)(h0 + r) * Kdim + cb * 8;
        bdst[s] = r * BK + ((cb ^ (r & 7)) * 8);
    }

    f32x4 zero; zero[0] = 0.f; zero[1] = 0.f; zero[2] = 0.f; zero[3] = 0.f;
    f32x4 acc[2][8];
    #pragma unroll
    for (int a = 0; a < 2; ++a)
        #pragma unroll
        for (int b = 0; b < 8; ++b) acc[a][b] = zero;

    f32x4 stB0[4][2], stB1[4][2];

    auto ldB0 = [&](int t) {
        int k0 = t * BK;
        #pragma unroll
        for (int s = 0; s < 4; ++s) {
            stB0[s][0] = *(const f32x4*)(bsrc[s] + k0);
            stB0[s][1] = *(const f32x4*)(bsrc[s] + k0 + 4);
        }
    };
    auto ldB1 = [&](int t) {
        int k0 = t * BK;
        #pragma unroll
        for (int s = 0; s < 4; ++s) {
            stB1[s][0] = *(const f32x4*)(bsrc[s] + k0);
            stB1[s][1] = *(const f32x4*)(bsrc[s] + k0 + 4);
        }
    };
    auto dswB0 = [&]() {
        #pragma unroll
        for (int s = 0; s < 4; ++s)
            *(ushort8*)(&Bs[0][bdst[s]]) = cvt8(stB0[s][0], stB0[s][1]);
    };
    auto dswB1 = [&]() {
        #pragma unroll
        for (int s = 0; s < 4; ++s)
            *(ushort8*)(&Bs[1][bdst[s]]) = cvt8(stB1[s][0], stB1[s][1]);
    };
    auto mmaStep = [&](int buf) {
        #pragma unroll
        for (int ks = 0; ks < 2; ++ks) {
            short8 a[2];
            #pragma unroll
            for (int fm = 0; fm < 2; ++fm) {
                int row = w * 32 + fm * 16 + (lane & 15);
                int cb = ks * 4 + (lane >> 4);
                a[fm] = *(const short8*)(&As[buf][row * BK + ((cb ^ (row & 7)) * 8)]);
            }
            #pragma unroll
            for (int fn = 0; fn < 8; ++fn) {
                int brow = fn * 16 + (lane & 15);
                int cb = ks * 4 + (lane >> 4);
                short8 b = *(const short8*)(&Bs[buf][brow * BK + ((cb ^ (brow & 7)) * 8)]);
                acc[0][fn] = mfma16(a[0], b, acc[0][fn]);
                acc[1][fn] = mfma16(a[1], b, acc[1][fn]);
            }
        }
    };

    const int NK = Kdim / BK; // 22 or 44, even
    gldA(0, 0);
    ldB0(0); dswB0();
    ldB1(1);
    __syncthreads();
    for (int t = 0; t < NK; t += 2) {
        if (t + 1 < NK) gldA(t + 1, 1);
        if (t + 2 < NK) ldB0(t + 2);
        mmaStep(0);
        if (t + 1 < NK) dswB1();
        __syncthreads();
        if (t + 1 < NK) {
            if (t + 2 < NK) gldA(t + 2, 0);
            if (t + 3 < NK) ldB1(t + 3);
            mmaStep(1);
            if (t + 2 < NK) dswB0();
            __syncthreads();
        }
    }

    int r0 = (lane >> 4) * 4, cc = lane & 15;
    #pragma unroll
    for (int fm = 0; fm < 2; ++fm) {
        #pragma unroll
        for (int r = 0; r < 4; ++r) {
            int p = m0 + w * 32 + fm * 16 + r0 + r;
            if (p < n) {
                if (wl) {
                    float wt = wl[seg + p];
                    size_t ob = (size_t)(seg + p) * H_DIM + h0 + cc;
                    #pragma unroll
                    for (int fn = 0; fn < 8; ++fn)
                        y_r[ob + fn * 16] = f2bf(acc[fm][fn][r] * wt);
                } else {
                    size_t ob = (size_t)p * H_DIM + h0 + cc;
                    #pragma unroll
                    for (int fn = 0; fn < 8; ++fn)
                        out[ob + fn * 16] = acc[fm][fn][r];
                }
            }
        }
    }
}

// ---------------- combine: out[t,:] += sum_k y_r[slot(t,k),:] ----------------
__global__ __launch_bounds__(256) void k_combine(const u16* __restrict__ y_r,
        const int* __restrict__ slot_of, float* __restrict__ out) {
    int t = blockIdx.x;
    int c = threadIdx.x * 8;
    int sl[8];
    #pragma unroll
    for (int k = 0; k < 8; ++k) sl[k] = slot_of[t * 8 + k];
    float s[8];
    f32x4 o0 = *(const f32x4*)(out + (size_t)t * H_DIM + c);
    f32x4 o1 = *(const f32x4*)(out + (size_t)t * H_DIM + c + 4);
    #pragma unroll
    for (int j = 0; j < 4; ++j) { s[j] = o0[j]; s[4 + j] = o1[j]; }
    #pragma unroll
    for (int k = 0; k < 8; ++k) {
        ushort8 v = *(const ushort8*)(y_r + (size_t)sl[k] * H_DIM + c);
        #pragma unroll
        for (int j = 0; j < 8; ++j) s[j] += bf2f(v[j]);
    }
    f32x4 r0, r1;
    #pragma unroll
    for (int j = 0; j < 4; ++j) { r0[j] = s[j]; r1[j] = s[4 + j]; }
    *(f32x4*)(out + (size_t)t * H_DIM + c) = r0;
    *(f32x4*)(out + (size_t)t * H_DIM + c + 4) = r1;
}

extern "C" void kernel_launch(void* const* d_in, const int* in_sizes, int n_in,
                              void* d_out, int out_size, void* d_ws, size_t ws_size,
                              hipStream_t stream) {
    const float* x         = (const float*)d_in[0];
    const float* gate_w    = (const float*)d_in[1];
    const float* e_bias    = (const float*)d_in[2];
    const float* gate_proj = (const float*)d_in[3];
    const float* up_proj   = (const float*)d_in[4];
    const float* down_proj = (const float*)d_in[5];
    const float* sgw       = (const float*)d_in[6];
    const float* suw       = (const float*)d_in[7];
    const float* sdw       = (const float*)d_in[8];
    float* out = (float*)d_out;

    char* ws = (char*)d_ws;
    size_t off = 0;
    auto alloc = [&](size_t bytes) -> char* {
        char* p = ws + off;
        off += (bytes + 255) & ~(size_t)255;
        return p;
    };
    int*   topk_idx = (int*)  alloc((size_t)T_TOK * 8 * 4);
    float* topk_w   = (float*)alloc((size_t)T_TOK * 8 * 4);
    int*   counts   = (int*)  alloc(256);   // [64]
    int*   offsets  = (int*)  alloc(512);   // [65]
    int*   fill     = (int*)  alloc(256);   // [64]
    int*   tiles_gu = (int*)  alloc(MAXT * 4);
    int*   tiles_dn = (int*)  alloc(MAXT * 4);
    int*   tok_list = (int*)  alloc((size_t)T_TOK * 8 * 4);
    float* w_list   = (float*)alloc((size_t)T_TOK * 8 * 4);
    int*   slot_of  = (int*)  alloc((size_t)T_TOK * 8 * 4);
    u16*   xb       = (u16*)  alloc((size_t)T_TOK * H_DIM * 2);
    u16*   inter_r  = (u16*)  alloc((size_t)T_TOK * 8 * I_DIM * 2);
    u16*   inter_s  = (u16*)  alloc((size_t)T_TOK * SI_DIM * 2);
    u16*   y_r      = (u16*)  alloc((size_t)T_TOK * 8 * H_DIM * 2);

    hipMemsetAsync(counts, 0, 1024, stream); // counts + offsets + fill

    k_cvt<<<(T_TOK * H_DIM) / 2048, 256, 0, stream>>>(x, xb);
    k_gate_fused<<<T_TOK / 8, 256, 0, stream>>>(x, gate_w, e_bias,
                                                topk_idx, topk_w, counts);
    k_prefix<<<1, 64, 0, stream>>>(counts, offsets, tiles_gu, tiles_dn);
    k_scatter<<<(T_TOK * 8) / 256, 256, 0, stream>>>(topk_idx, topk_w, offsets, fill,
                                                     tok_list, w_list, slot_of);

    // one gateup launch covering routed + shared experts
    k_gateup<<<dim3(MAXT, I_DIM / 64), 256, 0, stream>>>(
        xb, gate_proj, up_proj, sgw, suw, offsets, tok_list, tiles_gu,
        inter_r, inter_s);
    // one down launch; shared path plain-stores out, routed stores y_r partials
    k_down<<<dim3(MAXT, H_DIM / 128), 256, 0, stream>>>(
        inter_r, inter_s, down_proj, sdw, offsets, tok_list, tiles_dn,
        w_list, y_r, out);
    // gather 8 weighted routed partials per token into out
    k_combine<<<T_TOK, 256, 0, stream>>>(y_r, slot_of, out);
}

// Round 23
// 1085.933 us; speedup vs baseline: 1.6231x; 1.0010x over previous
//
#include <hip/hip_runtime.h>

typedef unsigned short u16;
typedef unsigned int u32;
typedef __attribute__((ext_vector_type(8))) short short8;
typedef __attribute__((ext_vector_type(8))) u16 ushort8;
typedef __attribute__((ext_vector_type(4))) float f32x4;
typedef __attribute__((ext_vector_type(4))) u32 u32x4;

#define T_TOK 2048
#define H_DIM 2048
#define NEXP 64
#define I_DIM 1408
#define SI_DIM 2816
#define BM 128
#define BK 64
#define MAXT 512

__device__ __forceinline__ u16 f2bf(float f) {
    u32 u = __builtin_bit_cast(u32, f);
    u32 r = u + 0x7FFFu + ((u >> 16) & 1u);
    return (u16)(r >> 16);
}

__device__ __forceinline__ float bf2f(u16 v) {
    u32 u = ((u32)v) << 16;
    return __builtin_bit_cast(float, u);
}

// HW packed f32->bf16 (RNE) — one VALU op per 2 elements (guide T12 recipe).
__device__ __forceinline__ u32 cvtpk(float lo, float hi) {
    u32 r;
    asm("v_cvt_pk_bf16_f32 %0, %1, %2" : "=v"(r) : "v"(lo), "v"(hi));
    return r;
}

__device__ __forceinline__ ushort8 cvt8(f32x4 a, f32x4 b) {
    u32x4 p;
    p[0] = cvtpk(a[0], a[1]);
    p[1] = cvtpk(a[2], a[3]);
    p[2] = cvtpk(b[0], b[1]);
    p[3] = cvtpk(b[2], b[3]);
    return __builtin_bit_cast(ushort8, p);
}

__device__ __forceinline__ f32x4 mfma16(short8 a, short8 b, f32x4 c) {
    return __builtin_amdgcn_mfma_f32_16x16x32_bf16(a, b, c, 0, 0, 0);
}

__device__ __forceinline__ void gld_lds16(const void* g, void* l) {
    __builtin_amdgcn_global_load_lds(
        (const __attribute__((address_space(1))) void*)(g),
        (__attribute__((address_space(3))) void*)(l), 16, 0, 0);
}

// ---- gating: f64-accurate logits + in-block top-k + fused x->bf16 copy ----
// 8 tokens/block. Logits stay in LDS; threads 0..7 run the serial
// group-restricted top-k (identical math to the reference path). While each
// 64-col chunk of x is staged in LDS, 64 threads emit the bf16 copy of it.
__global__ __launch_bounds__(256) void k_gate_fused(const float* __restrict__ x,
        const float* __restrict__ gw, const float* __restrict__ ebias,
        u16* __restrict__ xb,
        int* __restrict__ topk_idx, float* __restrict__ topk_w,
        int* __restrict__ counts) {
    __shared__ float xs[8][65];
    __shared__ float wsh[64][65];
    __shared__ float lg[8][65];     // logits (padded)
    __shared__ float bsh[64];
    int tid = threadIdx.x;
    int t0 = blockIdx.x * 8;
    if (tid < 64) bsh[tid] = ebias[tid];
    double acc0 = 0.0, acc1 = 0.0;
    int e = tid & 63, tg = tid >> 6; // tg in [0,4)
    for (int k0 = 0; k0 < H_DIM; k0 += 64) {
        #pragma unroll
        for (int s = 0; s < 2; ++s) {
            int idx = s * 256 + tid;
            int r = idx >> 6, k = idx & 63;
            xs[r][k] = x[(size_t)(t0 + r) * H_DIM + k0 + k];
        }
        #pragma unroll
        for (int s = 0; s < 16; ++s) {
            int idx = s * 256 + tid;
            int r = idx >> 6, k = idx & 63;
            wsh[r][k] = gw[(size_t)r * H_DIM + k0 + k];
        }
        __syncthreads();
        // fused bf16 copy of this x chunk (threads 0..63, one ushort8 each)
        if (tid < 64) {
            int r = tid >> 3, c8 = (tid & 7) * 8;
            f32x4 v0, v1;
            #pragma unroll
            for (int j = 0; j < 4; ++j) { v0[j] = xs[r][c8 + j]; v1[j] = xs[r][c8 + 4 + j]; }
            *(ushort8*)(xb + (size_t)(t0 + r) * H_DIM + k0 + c8) = cvt8(v0, v1);
        }
        #pragma unroll 8
        for (int k = 0; k < 64; ++k) {
            double wv = (double)wsh[e][k];
            acc0 += (double)xs[tg][k] * wv;
            acc1 += (double)xs[tg + 4][k] * wv;
        }
        __syncthreads();
    }
    lg[tg][e] = (float)acc0;
    lg[tg + 4][e] = (float)acc1;
    __syncthreads();

    if (tid < 8) {
        int t = t0 + tid;
        float sc[64];
        #pragma unroll
        for (int e2 = 0; e2 < 64; ++e2)
            sc[e2] = 1.0f / (1.0f + expf(-lg[tid][e2]));
        float gsc[8];
        #pragma unroll
        for (int g = 0; g < 8; ++g) {
            float m1 = -1e30f, m2 = -1e30f;
            #pragma unroll
            for (int j = 0; j < 8; ++j) {
                float v = sc[g * 8 + j] + bsh[g * 8 + j];
                if (v > m1) { m2 = m1; m1 = v; }
                else if (v > m2) { m2 = v; }
            }
            gsc[g] = m1 + m2;
        }
        u32 gmask = 0;
        #pragma unroll
        for (int it = 0; it < 4; ++it) {
            float best = -1e30f; int bi = 0;
            #pragma unroll
            for (int g = 0; g < 8; ++g) {
                bool ok = !((gmask >> g) & 1u);
                if (ok && gsc[g] > best) { best = gsc[g]; bi = g; }
            }
            gmask |= 1u << bi;
        }
        unsigned long long avail = 0ull;
        #pragma unroll
        for (int g = 0; g < 8; ++g)
            if ((gmask >> g) & 1u) avail |= (0xFFull << (g * 8));
        float wsum = 0.f;
        int idx[8]; float wv[8];
        #pragma unroll
        for (int it = 0; it < 8; ++it) {
            float best = -1e30f, bw = 0.f; int bi = 0;
            #pragma unroll
            for (int e2 = 0; e2 < 64; ++e2) {
                bool ok = (avail >> e2) & 1ull;
                float v = sc[e2] + bsh[e2];
                if (ok && v > best) { best = v; bi = e2; bw = sc[e2]; }
            }
            avail &= ~(1ull << bi);
            idx[it] = bi; wv[it] = bw; wsum += bw;
        }
        float scale = 2.5f / (wsum + 1e-20f);
        #pragma unroll
        for (int it = 0; it < 8; ++it) {
            topk_idx[t * 8 + it] = idx[it];
            topk_w[t * 8 + it] = wv[it] * scale;
            atomicAdd(&counts[idx[it]], 1);
        }
    }
}

// ---------------- parallel prefix + XCD-grouped tile lists (1 wave) ---------
__global__ __launch_bounds__(64) void k_prefix(const int* __restrict__ counts,
        int* __restrict__ offsets, int* __restrict__ tiles_gu, int* __restrict__ tiles_dn) {
    int e = threadIdx.x;            // one wave of 64
    #pragma unroll
    for (int j = 0; j < MAXT / 64; ++j) {
        tiles_gu[e + j * 64] = -1;
        tiles_dn[e + j * 64] = -1;
    }
    __syncthreads();

    int c = counts[e];
    int sum = c;
    #pragma unroll
    for (int d = 1; d < 64; d <<= 1) {
        int v = __shfl_up(sum, d, 64);
        if (e >= d) sum += v;
    }
    offsets[e] = sum - c;
    if (e == 63) offsets[64] = sum;

    int nt = (c + BM - 1) / BM;
    int ssum = nt;
    #pragma unroll
    for (int d = 8; d < 64; d <<= 1) {
        int v = __shfl_up(ssum, d, 64);
        if (e >= d) ssum += v;
    }
    int slotbase = ssum - nt;
    int xcd = e & 7;
    int shg = (43 - xcd) / 8 + 1;   // 44 gateup panels: xcd<4 -> 6, else 5
    int shd = 2;                    // 16 down panels: 2 per xcd

    if (e < SI_DIM / 64) tiles_gu[(e & 7) + 8 * (e >> 3)] = (64 << 16) | (e * 64);
    if (e < H_DIM / 128) tiles_dn[(e & 7) + 8 * (e >> 3)] = (64 << 16) | (e * 128);

    for (int i = 0; i < nt; ++i) {
        int m0 = i * BM;
        int pg = xcd + 8 * (shg + slotbase + i);
        if (pg < MAXT) tiles_gu[pg] = (e << 16) | m0;
        int pd = xcd + 8 * (shd + slotbase + i);
        if (pd < MAXT) tiles_dn[pd] = (e << 16) | m0;
    }
}

// ---------------- scatter (t,k) -> per-expert lists + inverse slot map ------
__global__ __launch_bounds__(256) void k_scatter(const int* __restrict__ topk_idx,
        const float* __restrict__ topk_w, const int* __restrict__ offsets,
        int* __restrict__ fill, int* __restrict__ tok_list, float* __restrict__ w_list,
        int* __restrict__ slot_of) {
    int gid = blockIdx.x * 256 + threadIdx.x;
    int t = gid >> 3;
    int e = topk_idx[gid];
    int pos = offsets[e] + atomicAdd(&fill[e], 1);
    tok_list[pos] = t;
    w_list[pos] = topk_w[gid];
    slot_of[gid] = pos;
}

// ---------------- unified gate+up+silu*mul grouped GEMM ----------------
// 128m x 64n(gate+up), BK=64, 4 waves, dbuf LDS, one barrier/K-step.
// A: global_load_lds direct (source-preswizzled, linear LDS), issued one step
// ahead into the other buffer. B: f32->bf16 (v_cvt_pk) depth-2 register staging.
__global__ __launch_bounds__(256, 2) void k_gateup(
        const u16* __restrict__ xb,
        const float* __restrict__ gr, const float* __restrict__ ur,
        const float* __restrict__ gs, const float* __restrict__ us,
        const int* __restrict__ offsets, const int* __restrict__ tok_list,
        const int* __restrict__ tiles,
        u16* __restrict__ inter_r, u16* __restrict__ inter_s) {
    int tt = tiles[blockIdx.x];
    if (tt < 0) return;
    int e = tt >> 16;
    const float *Bg, *Bu; u16* op; const int* tl;
    int m0, seg, n, i0, Irows;
    if (e < 64) {
        m0 = tt & 0xFFFF; seg = offsets[e]; n = offsets[e + 1] - seg;
        if (n <= 0 || m0 >= n) return;
        i0 = blockIdx.y * 64;
        Bg = gr + (size_t)e * I_DIM * H_DIM;
        Bu = ur + (size_t)e * I_DIM * H_DIM;
        op = inter_r; Irows = I_DIM; tl = tok_list;
    } else {
        if (blockIdx.y >= T_TOK / BM) return;
        i0 = tt & 0xFFFF; m0 = blockIdx.y * BM; seg = 0; n = T_TOK;
        Bg = gs; Bu = us;
        op = inter_s; Irows = SI_DIM; tl = nullptr;
    }

    __shared__ u16 As[2][BM * BK];    // 2 x 16KB, linear (source-preswizzled)
    __shared__ u16 Bsg[2][64 * BK];   // 2 x 8KB, xor-swizzled
    __shared__ u16 Bsu[2][64 * BK];   // 2 x 8KB

    int tid = threadIdx.x;
    int w = tid >> 6, lane = tid & 63;

    const u16* agsrc[4];
    #pragma unroll
    for (int s = 0; s < 4; ++s) {
        int slot = s * 256 + tid;
        int r = slot >> 3, cb = slot & 7;
        int p = m0 + r; if (p >= n) p = n - 1;
        int tok = tl ? tl[seg + p] : p;
        agsrc[s] = xb + (size_t)tok * H_DIM + ((cb ^ (r & 7)) * 8);
    }
    auto gldA = [&](int t, int buf) {
        #pragma unroll
        for (int s = 0; s < 4; ++s)
            gld_lds16(agsrc[s] + t * BK, (u16*)As[buf] + s * 2048 + w * 512);
    };

    const float* bgsrc[2]; const float* busrc[2]; int bdst[2];
    #pragma unroll
    for (int s = 0; s < 2; ++s) {
        int slot = s * 256 + tid;
        int r = slot >> 3, cb = slot & 7;
        bgsrc[s] = Bg + (size_t)(i0 + r) * H_DIM + cb * 8;
        busrc[s] = Bu + (size_t)(i0 + r) * H_DIM + cb * 8;
        bdst[s] = r * BK + ((cb ^ (r & 7)) * 8);
    }

    f32x4 zero; zero[0] = 0.f; zero[1] = 0.f; zero[2] = 0.f; zero[3] = 0.f;
    f32x4 accg[2][4], accu[2][4];
    #pragma unroll
    for (int a = 0; a < 2; ++a)
        #pragma unroll
        for (int b = 0; b < 4; ++b) { accg[a][b] = zero; accu[a][b] = zero; }

    f32x4 stG0[2][2], stU0[2][2], stG1[2][2], stU1[2][2];

    auto ldB0 = [&](int t) {
        int k0 = t * BK;
        #pragma unroll
        for (int s = 0; s < 2; ++s) {
            stG0[s][0] = *(const f32x4*)(bgsrc[s] + k0);
            stG0[s][1] = *(const f32x4*)(bgsrc[s] + k0 + 4);
            stU0[s][0] = *(const f32x4*)(busrc[s] + k0);
            stU0[s][1] = *(const f32x4*)(busrc[s] + k0 + 4);
        }
    };
    auto ldB1 = [&](int t) {
        int k0 = t * BK;
        #pragma unroll
        for (int s = 0; s < 2; ++s) {
            stG1[s][0] = *(const f32x4*)(bgsrc[s] + k0);
            stG1[s][1] = *(const f32x4*)(bgsrc[s] + k0 + 4);
            stU1[s][0] = *(const f32x4*)(busrc[s] + k0);
            stU1[s][1] = *(const f32x4*)(busrc[s] + k0 + 4);
        }
    };
    auto dswB0 = [&]() {
        #pragma unroll
        for (int s = 0; s < 2; ++s) {
            *(ushort8*)(&Bsg[0][bdst[s]]) = cvt8(stG0[s][0], stG0[s][1]);
            *(ushort8*)(&Bsu[0][bdst[s]]) = cvt8(stU0[s][0], stU0[s][1]);
        }
    };
    auto dswB1 = [&]() {
        #pragma unroll
        for (int s = 0; s < 2; ++s) {
            *(ushort8*)(&Bsg[1][bdst[s]]) = cvt8(stG1[s][0], stG1[s][1]);
            *(ushort8*)(&Bsu[1][bdst[s]]) = cvt8(stU1[s][0], stU1[s][1]);
        }
    };
    auto mmaStep = [&](int buf) {
        #pragma unroll
        for (int ks = 0; ks < 2; ++ks) {
            short8 a[2];
            #pragma unroll
            for (int fm = 0; fm < 2; ++fm) {
                int row = w * 32 + fm * 16 + (lane & 15);
                int cb = ks * 4 + (lane >> 4);
                a[fm] = *(const short8*)(&As[buf][row * BK + ((cb ^ (row & 7)) * 8)]);
            }
            #pragma unroll
            for (int fn = 0; fn < 4; ++fn) {
                int brow = fn * 16 + (lane & 15);
                int cb = ks * 4 + (lane >> 4);
                int boff = brow * BK + ((cb ^ (brow & 7)) * 8);
                short8 bg = *(const short8*)(&Bsg[buf][boff]);
                short8 bu = *(const short8*)(&Bsu[buf][boff]);
                accg[0][fn] = mfma16(a[0], bg, accg[0][fn]);
                accg[1][fn] = mfma16(a[1], bg, accg[1][fn]);
                accu[0][fn] = mfma16(a[0], bu, accu[0][fn]);
                accu[1][fn] = mfma16(a[1], bu, accu[1][fn]);
            }
        }
    };

    const int NK = H_DIM / BK; // 32, even
    gldA(0, 0);
    ldB0(0); dswB0();
    ldB1(1);
    __syncthreads();
    for (int t = 0; t < NK; t += 2) {
        if (t + 1 < NK) gldA(t + 1, 1);
        if (t + 2 < NK) ldB0(t + 2);
        mmaStep(0);
        if (t + 1 < NK) dswB1();
        __syncthreads();
        if (t + 1 < NK) {
            if (t + 2 < NK) gldA(t + 2, 0);
            if (t + 3 < NK) ldB1(t + 3);
            mmaStep(1);
            if (t + 2 < NK) dswB0();
            __syncthreads();
        }
    }

    int r0 = (lane >> 4) * 4, cc = lane & 15;
    #pragma unroll
    for (int fm = 0; fm < 2; ++fm) {
        #pragma unroll
        for (int r = 0; r < 4; ++r) {
            int p = m0 + w * 32 + fm * 16 + r0 + r;
            if (p < n) {
                size_t rowb = (size_t)(seg + p) * Irows + i0;
                #pragma unroll
                for (int fn = 0; fn < 4; ++fn) {
                    float g = accg[fm][fn][r], u = accu[fm][fn][r];
                    float val = g / (1.0f + expf(-g)) * u;
                    op[rowb + fn * 16 + cc] = f2bf(val);
                }
            }
        }
    }
}

// ---------------- unified down-proj grouped GEMM (NO atomics) ----------------
// 128m x 128n, BK=64, 4 waves. A via gld_lds (one step ahead), B depth-2 regs.
// Routed: weighted bf16 partials to y_r. Shared: plain f32 store to out.
__global__ __launch_bounds__(256, 2) void k_down(
        const u16* __restrict__ inter_r, const u16* __restrict__ inter_s,
        const float* __restrict__ dr, const float* __restrict__ dsw,
        const int* __restrict__ offsets, const int* __restrict__ tok_list,
        const int* __restrict__ tiles,
        const float* __restrict__ w_list,
        u16* __restrict__ y_r, float* __restrict__ out) {
    int tt = tiles[blockIdx.x];
    if (tt < 0) return;
    int e = tt >> 16;
    const float* Bd; const u16* interp; const float* wl;
    int m0, seg, n, h0, Kdim;
    if (e < 64) {
        m0 = tt & 0xFFFF; seg = offsets[e]; n = offsets[e + 1] - seg;
        if (n <= 0 || m0 >= n) return;
        h0 = blockIdx.y * 128;
        Bd = dr + (size_t)e * H_DIM * I_DIM;
        interp = inter_r; Kdim = I_DIM; wl = w_list;
    } else {
        h0 = tt & 0xFFFF; m0 = blockIdx.y * BM; seg = 0; n = T_TOK;
        Bd = dsw; interp = inter_s; Kdim = SI_DIM; wl = nullptr;
    }

    __shared__ u16 As[2][BM * BK];    // 2 x 16KB, linear (source-preswizzled)
    __shared__ u16 Bs[2][128 * BK];   // 2 x 16KB, xor-swizzled

    int tid = threadIdx.x;
    int w = tid >> 6, lane = tid & 63;

    const u16* agsrc[4];
    #pragma unroll
    for (int s = 0; s < 4; ++s) {
        int slot = s * 256 + tid;
        int r = slot >> 3, cb = slot & 7;
        int p = m0 + r; if (p >= n) p = n - 1;
        agsrc[s] = interp + (size_t)(seg + p) * Kdim + ((cb ^ (r & 7)) * 8);
    }
    auto gldA = [&](int t, int buf) {
        #pragma unroll
        for (int s = 0; s < 4; ++s)
            gld_lds16(agsrc[s] + t * BK, (u16*)As[buf] + s * 2048 + w * 512);
    };

    const float* bsrc[4]; int bdst[4];
    #pragma unroll
    for (int s = 0; s < 4; ++s) {
        int slot = s * 256 + tid;
        int r = slot >> 3, cb = slot & 7;
        bsrc[s] = Bd + (size_t)(h0 + r) * Kdim + cb * 8;
        bdst[s] = r * BK + ((cb ^ (r & 7)) * 8);
    }

    f32x4 zero; zero[0] = 0.f; zero[1] = 0.f; zero[2] = 0.f; zero[3] = 0.f;
    f32x4 acc[2][8];
    #pragma unroll
    for (int a = 0; a < 2; ++a)
        #pragma unroll
        for (int b = 0; b < 8; ++b) acc[a][b] = zero;

    f32x4 stB0[4][2], stB1[4][2];

    auto ldB0 = [&](int t) {
        int k0 = t * BK;
        #pragma unroll
        for (int s = 0; s < 4; ++s) {
            stB0[s][0] = *(const f32x4*)(bsrc[s] + k0);
            stB0[s][1] = *(const f32x4*)(bsrc[s] + k0 + 4);
        }
    };
    auto ldB1 = [&](int t) {
        int k0 = t * BK;
        #pragma unroll
        for (int s = 0; s < 4; ++s) {
            stB1[s][0] = *(const f32x4*)(bsrc[s] + k0);
            stB1[s][1] = *(const f32x4*)(bsrc[s] + k0 + 4);
        }
    };
    auto dswB0 = [&]() {
        #pragma unroll
        for (int s = 0; s < 4; ++s)
            *(ushort8*)(&Bs[0][bdst[s]]) = cvt8(stB0[s][0], stB0[s][1]);
    };
    auto dswB1 = [&]() {
        #pragma unroll
        for (int s = 0; s < 4; ++s)
            *(ushort8*)(&Bs[1][bdst[s]]) = cvt8(stB1[s][0], stB1[s][1]);
    };
    auto mmaStep = [&](int buf) {
        #pragma unroll
        for (int ks = 0; ks < 2; ++ks) {
            short8 a[2];
            #pragma unroll
            for (int fm = 0; fm < 2; ++fm) {
                int row = w * 32 + fm * 16 + (lane & 15);
                int cb = ks * 4 + (lane >> 4);
                a[fm] = *(const short8*)(&As[buf][row * BK + ((cb ^ (row & 7)) * 8)]);
            }
            #pragma unroll
            for (int fn = 0; fn < 8; ++fn) {
                int brow = fn * 16 + (lane & 15);
                int cb = ks * 4 + (lane >> 4);
                short8 b = *(const short8*)(&Bs[buf][brow * BK + ((cb ^ (brow & 7)) * 8)]);
                acc[0][fn] = mfma16(a[0], b, acc[0][fn]);
                acc[1][fn] = mfma16(a[1], b, acc[1][fn]);
            }
        }
    };

    const int NK = Kdim / BK; // 22 or 44, even
    gldA(0, 0);
    ldB0(0); dswB0();
    ldB1(1);
    __syncthreads();
    for (int t = 0; t < NK; t += 2) {
        if (t + 1 < NK) gldA(t + 1, 1);
        if (t + 2 < NK) ldB0(t + 2);
        mmaStep(0);
        if (t + 1 < NK) dswB1();
        __syncthreads();
        if (t + 1 < NK) {
            if (t + 2 < NK) gldA(t + 2, 0);
            if (t + 3 < NK) ldB1(t + 3);
            mmaStep(1);
            if (t + 2 < NK) dswB0();
            __syncthreads();
        }
    }

    int r0 = (lane >> 4) * 4, cc = lane & 15;
    #pragma unroll
    for (int fm = 0; fm < 2; ++fm) {
        #pragma unroll
        for (int r = 0; r < 4; ++r) {
            int p = m0 + w * 32 + fm * 16 + r0 + r;
            if (p < n) {
                if (wl) {
                    float wt = wl[seg + p];
                    size_t ob = (size_t)(seg + p) * H_DIM + h0 + cc;
                    #pragma unroll
                    for (int fn = 0; fn < 8; ++fn)
                        y_r[ob + fn * 16] = f2bf(acc[fm][fn][r] * wt);
                } else {
                    size_t ob = (size_t)p * H_DIM + h0 + cc;
                    #pragma unroll
                    for (int fn = 0; fn < 8; ++fn)
                        out[ob + fn * 16] = acc[fm][fn][r];
                }
            }
        }
    }
}

// ---------------- combine: out[t,:] += sum_k y_r[slot(t,k),:] ----------------
__global__ __launch_bounds__(256) void k_combine(const u16* __restrict__ y_r,
        const int* __restrict__ slot_of, float* __restrict__ out) {
    int t = blockIdx.x;
    int c = threadIdx.x * 8;
    int sl[8];
    #pragma unroll
    for (int k = 0; k < 8; ++k) sl[k] = slot_of[t * 8 + k];
    float s[8];
    f32x4 o0 = *(const f32x4*)(out + (size_t)t * H_DIM + c);
    f32x4 o1 = *(const f32x4*)(out + (size_t)t * H_DIM + c + 4);
    #pragma unroll
    for (int j = 0; j < 4; ++j) { s[j] = o0[j]; s[4 + j] = o1[j]; }
    #pragma unroll
    for (int k = 0; k < 8; ++k) {
        ushort8 v = *(const ushort8*)(y_r + (size_t)sl[k] * H_DIM + c);
        #pragma unroll
        for (int j = 0; j < 8; ++j) s[j] += bf2f(v[j]);
    }
    f32x4 r0, r1;
    #pragma unroll
    for (int j = 0; j < 4; ++j) { r0[j] = s[j]; r1[j] = s[4 + j]; }
    *(f32x4*)(out + (size_t)t * H_DIM + c) = r0;
    *(f32x4*)(out + (size_t)t * H_DIM + c + 4) = r1;
}

extern "C" void kernel_launch(void* const* d_in, const int* in_sizes, int n_in,
                              void* d_out, int out_size, void* d_ws, size_t ws_size,
                              hipStream_t stream) {
    const float* x         = (const float*)d_in[0];
    const float* gate_w    = (const float*)d_in[1];
    const float* e_bias    = (const float*)d_in[2];
    const float* gate_proj = (const float*)d_in[3];
    const float* up_proj   = (const float*)d_in[4];
    const float* down_proj = (const float*)d_in[5];
    const float* sgw       = (const float*)d_in[6];
    const float* suw       = (const float*)d_in[7];
    const float* sdw       = (const float*)d_in[8];
    float* out = (float*)d_out;

    char* ws = (char*)d_ws;
    size_t off = 0;
    auto alloc = [&](size_t bytes) -> char* {
        char* p = ws + off;
        off += (bytes + 255) & ~(size_t)255;
        return p;
    };
    int*   topk_idx = (int*)  alloc((size_t)T_TOK * 8 * 4);
    float* topk_w   = (float*)alloc((size_t)T_TOK * 8 * 4);
    int*   counts   = (int*)  alloc(256);   // [64]
    int*   offsets  = (int*)  alloc(512);   // [65]
    int*   fill     = (int*)  alloc(256);   // [64]
    int*   tiles_gu = (int*)  alloc(MAXT * 4);
    int*   tiles_dn = (int*)  alloc(MAXT * 4);
    int*   tok_list = (int*)  alloc((size_t)T_TOK * 8 * 4);
    float* w_list   = (float*)alloc((size_t)T_TOK * 8 * 4);
    int*   slot_of  = (int*)  alloc((size_t)T_TOK * 8 * 4);
    u16*   xb       = (u16*)  alloc((size_t)T_TOK * H_DIM * 2);
    u16*   inter_r  = (u16*)  alloc((size_t)T_TOK * 8 * I_DIM * 2);
    u16*   inter_s  = (u16*)  alloc((size_t)T_TOK * SI_DIM * 2);
    u16*   y_r      = (u16*)  alloc((size_t)T_TOK * 8 * H_DIM * 2);

    hipMemsetAsync(counts, 0, 1024, stream); // counts + offsets + fill

    k_gate_fused<<<T_TOK / 8, 256, 0, stream>>>(x, gate_w, e_bias, xb,
                                                topk_idx, topk_w, counts);
    k_prefix<<<1, 64, 0, stream>>>(counts, offsets, tiles_gu, tiles_dn);
    k_scatter<<<(T_TOK * 8) / 256, 256, 0, stream>>>(topk_idx, topk_w, offsets, fill,
                                                     tok_list, w_list, slot_of);

    // one gateup launch covering routed + shared experts
    k_gateup<<<dim3(MAXT, I_DIM / 64), 256, 0, stream>>>(
        xb, gate_proj, up_proj, sgw, suw, offsets, tok_list, tiles_gu,
        inter_r, inter_s);
    // one down launch; shared path plain-stores out, routed stores y_r partials
    k_down<<<dim3(MAXT, H_DIM / 128), 256, 0, stream>>>(
        inter_r, inter_s, down_proj, sdw, offsets, tok_list, tiles_dn,
        w_list, y_r, out);
    // gather 8 weighted routed partials per token into out
    k_combine<<<T_TOK, 256, 0, stream>>>(y_r, slot_of, out);
}